// Round 5
// baseline (1173.330 us; speedup 1.0000x reference)
//
#include <hip/hip_runtime.h>
#include <math.h>

#define N_NODES 32768
#define N_EDGES 491520
#define F_IN    11
#define H       64
#define G_GRAPHS 2048
#define NN_PER_G 16
#define R_REACT 1024
#define L_LAYERS 4
#define EIN     129   // 2H+1
#define NIN     139   // 2H+F

typedef __attribute__((ext_vector_type(8))) short short8;
typedef __attribute__((ext_vector_type(4))) float f32x4;

__device__ __forceinline__ float silu_f(float x) {
    return x / (1.0f + __expf(-x));
}
__device__ __forceinline__ void atomAddF(float* p, float v) {
    unsafeAtomicAdd(p, v);
}
__device__ __forceinline__ float bf2f(unsigned short b) {
    union { float f; unsigned u; } v; v.u = ((unsigned)b) << 16;
    return v.f;
}
__device__ __forceinline__ unsigned short f2bf(float x) {   // RNE
    union { float f; unsigned u; } v; v.f = x;
    unsigned r = v.u + 0x7FFFu + ((v.u >> 16) & 1u);
    return (unsigned short)(r >> 16);
}
// RNE split: x ~= hi + lo with |residual| ~ 2^-17 relative (R3: absmax 0.0)
__device__ __forceinline__ void splitbf(float x, unsigned short& hi, unsigned short& lo) {
    hi = f2bf(x);
    lo = f2bf(x - bf2f(hi));
}

// ---------------- embed: h = h0 @ emb_w + emb_b ----------------
__global__ __launch_bounds__(256) void k_embed(
        const float* __restrict__ h0, const float* __restrict__ emb_w,
        const float* __restrict__ emb_b, float* __restrict__ h) {
    int tid = blockIdx.x * 256 + threadIdx.x;   // N*H threads
    int n = tid >> 6, j = tid & 63;
    float acc = emb_b[j];
#pragma unroll
    for (int k = 0; k < F_IN; ++k)
        acc += h0[n * F_IN + k] * emb_w[k * H + j];
    h[tid] = acc;
}

// ---------------- radial per edge ----------------
__global__ __launch_bounds__(256) void k_radial(
        const int* __restrict__ edges, const float* __restrict__ pos,
        float* __restrict__ radial) {
    int e = blockIdx.x * 256 + threadIdx.x;
    int r = edges[e], c = edges[N_EDGES + e];
    float dx = pos[r * 3 + 0] - pos[c * 3 + 0];
    float dy = pos[r * 3 + 1] - pos[c * 3 + 1];
    float dz = pos[r * 3 + 2] - pos[c * 3 + 2];
    radial[e] = dx * dx + dy * dy + dz * dz;
}

// ---------------- CSR build (once per launch) ----------------
__global__ __launch_bounds__(256) void k_hist(
        const int* __restrict__ edges, int* __restrict__ deg) {
    int e = blockIdx.x * 256 + threadIdx.x;
    atomicAdd(&deg[edges[e]], 1);
}

__global__ __launch_bounds__(128) void k_scan_blk(
        const int* __restrict__ deg, int* __restrict__ off,
        int* __restrict__ bsum) {
    __shared__ int sd[128];
    int b = blockIdx.x;                    // 256 blocks x 128 nodes
    sd[threadIdx.x] = deg[b * 128 + threadIdx.x];
    __syncthreads();
    if (threadIdx.x == 0) {
        int s = 0;
        for (int i = 0; i < 128; ++i) { int d = sd[i]; sd[i] = s; s += d; }
        bsum[b] = s;
    }
    __syncthreads();
    off[b * 128 + threadIdx.x] = sd[threadIdx.x];
}

__global__ __launch_bounds__(256) void k_scan_top(
        const int* __restrict__ bsum, int* __restrict__ bbase) {
    __shared__ int sb[256];
    sb[threadIdx.x] = bsum[threadIdx.x];
    __syncthreads();
    if (threadIdx.x == 0) {
        int s = 0;
        for (int i = 0; i < 256; ++i) { int d = sb[i]; sb[i] = s; s += d; }
    }
    __syncthreads();
    bbase[threadIdx.x] = sb[threadIdx.x];
}

__global__ __launch_bounds__(256) void k_cursor(
        const int* __restrict__ off, const int* __restrict__ bbase,
        int* __restrict__ nstart, int* __restrict__ cursor) {
    int n = blockIdx.x * 256 + threadIdx.x;
    int ns = off[n] + bbase[n >> 7];
    nstart[n] = ns;
    cursor[n] = ns;
    if (n == 0) nstart[N_NODES] = N_EDGES;
}

// scatter edges into CSR order; pre-gather col/radial/mask for coalesced reads
__global__ __launch_bounds__(256) void k_fill(
        const int* __restrict__ edges, const float* __restrict__ radial,
        const float* __restrict__ emask, int* __restrict__ cursor,
        int* __restrict__ csrP, float* __restrict__ csrR,
        float* __restrict__ csrM) {
    int e = blockIdx.x * 256 + threadIdx.x;
    int r = edges[e];
    int pos = atomicAdd(&cursor[r], 1);
    csrP[pos] = edges[N_EDGES + e] | ((r & 15) << 16);  // col | row_local
    csrR[pos] = radial[e];
    csrM[pos] = emask[e];
}

// ---------------- node projection via MFMA: PA = h@W1a+b1; PB = h@W1b ----
__global__ __launch_bounds__(64, 2) void k_nodeproj_m(
        const float* __restrict__ h, const float* __restrict__ W1,
        const float* __restrict__ b1,
        float* __restrict__ PA, float* __restrict__ PB) {
    const int lane = threadIdx.x;
    const int quad = lane >> 4, m16 = lane & 15;

    short8 Bh[16], Bl[16];     // [nt*2+kf]; nt 0..3 -> PA cols, 4..7 -> PB
#pragma unroll
    for (int nt = 0; nt < 8; ++nt) {
#pragma unroll
        for (int kf = 0; kf < 2; ++kf) {
            short8 bh, bl;
#pragma unroll
            for (int j = 0; j < 8; ++j) {
                int row = (nt >= 4 ? 64 : 0) + kf * 32 + quad * 8 + j;
                float w = W1[row * H + (nt & 3) * 16 + m16];
                unsigned short hi, lo; splitbf(w, hi, lo);
                bh[j] = (short)hi; bl[j] = (short)lo;
            }
            Bh[nt * 2 + kf] = bh; Bl[nt * 2 + kf] = bl;
        }
    }
    float b1v[4];
#pragma unroll
    for (int nt = 0; nt < 4; ++nt) b1v[nt] = b1[nt * 16 + m16];

    for (int t = 0; t < 8; ++t) {
        const int nb = (blockIdx.x * 8 + t) * 16;
        const float* hp = h + (nb + m16) * H + quad * 8;
        float av[16];
        *(float4*)&av[0]  = *(const float4*)(hp + 0);
        *(float4*)&av[4]  = *(const float4*)(hp + 4);
        *(float4*)&av[8]  = *(const float4*)(hp + 32);
        *(float4*)&av[12] = *(const float4*)(hp + 36);
        short8 Ah0, Ah1, Al0, Al1;
#pragma unroll
        for (int j = 0; j < 8; ++j) {
            unsigned short hi, lo;
            splitbf(av[j], hi, lo);     Ah0[j] = (short)hi; Al0[j] = (short)lo;
            splitbf(av[8 + j], hi, lo); Ah1[j] = (short)hi; Al1[j] = (short)lo;
        }
        f32x4 acc[8];
#pragma unroll
        for (int nt = 0; nt < 8; ++nt) {
            f32x4 a = {0.0f, 0.0f, 0.0f, 0.0f};
            a = __builtin_amdgcn_mfma_f32_16x16x32_bf16(Ah0, Bh[nt*2+0], a, 0, 0, 0);
            a = __builtin_amdgcn_mfma_f32_16x16x32_bf16(Ah1, Bh[nt*2+1], a, 0, 0, 0);
            a = __builtin_amdgcn_mfma_f32_16x16x32_bf16(Ah0, Bl[nt*2+0], a, 0, 0, 0);
            a = __builtin_amdgcn_mfma_f32_16x16x32_bf16(Ah1, Bl[nt*2+1], a, 0, 0, 0);
            a = __builtin_amdgcn_mfma_f32_16x16x32_bf16(Al0, Bh[nt*2+0], a, 0, 0, 0);
            a = __builtin_amdgcn_mfma_f32_16x16x32_bf16(Al1, Bh[nt*2+1], a, 0, 0, 0);
            acc[nt] = a;
        }
#pragma unroll
        for (int r4 = 0; r4 < 4; ++r4) {
            const int node = nb + quad * 4 + r4;
#pragma unroll
            for (int nt = 0; nt < 4; ++nt)
                PA[node * H + nt * 16 + m16] = acc[nt][r4] + b1v[nt];
#pragma unroll
            for (int nt = 4; nt < 8; ++nt)
                PB[node * H + (nt - 4) * 16 + m16] = acc[nt][r4];
        }
    }
}

// ---------------- edge MLP + LDS aggregation (no global atomics) ---------
// Block owns 16 nodes; processes all their incoming edges (CSR order).
__global__ __launch_bounds__(256, 2) void k_edge5(
        const float* __restrict__ PA, const float* __restrict__ PB,
        const int* __restrict__ nstart, const int* __restrict__ csrP,
        const float* __restrict__ csrR, const float* __restrict__ csrM,
        const float* __restrict__ W1,   // only row 128 (w1c) used
        const float* __restrict__ W2, const float* __restrict__ b2,
        float* __restrict__ agg) {
    const int g = blockIdx.x;
    const int tid = threadIdx.x;
    const int lane = tid & 63, wave = tid >> 6;
    const int quad = lane >> 4, m16 = lane & 15;

    __shared__ float aggld[16 * 64];
#pragma unroll
    for (int i = 0; i < 4; ++i) aggld[tid * 4 + i] = 0.0f;

    short8 Bh[8], Bl[8];             // W2 frags [nt*2+kf]
#pragma unroll
    for (int nt = 0; nt < 4; ++nt) {
#pragma unroll
        for (int kf = 0; kf < 2; ++kf) {
            short8 bh, bl;
#pragma unroll
            for (int j = 0; j < 8; ++j) {
                float w = W2[(kf * 32 + quad * 8 + j) * H + nt * 16 + m16];
                unsigned short hi, lo; splitbf(w, hi, lo);
                bh[j] = (short)hi; bl[j] = (short)lo;
            }
            Bh[nt * 2 + kf] = bh; Bl[nt * 2 + kf] = bl;
        }
    }
    float w1cr[16];
#pragma unroll
    for (int i = 0; i < 16; ++i) {
        int k = (i < 8) ? (quad * 8 + i) : (32 + quad * 8 + (i - 8));
        w1cr[i] = W1[128 * H + k];
    }
    float b2v[4];
#pragma unroll
    for (int nt = 0; nt < 4; ++nt) b2v[nt] = b2[nt * 16 + m16];

    const int start = nstart[g * 16];
    const int end   = nstart[g * 16 + 16];
    __syncthreads();

    const int ntiles = (end - start + 15) >> 4;
    for (int t = wave; t < ntiles; t += 4) {
        const int idx = start + t * 16 + m16;
        const bool valid = idx < end;
        const int srci = valid ? idx : start;
        const int pk = csrP[srci];
        const float rad = csrR[srci];
        const float msk = valid ? csrM[srci] : 0.0f;
        const int c  = pk & 0xFFFF;
        const int rl = pk >> 16;

        const float* par = PA + (g * 16 + rl) * H + quad * 8;
        const float* pbr = PB + c * H + quad * 8;
        float av[16], bv[16];
        *(float4*)&av[0]  = *(const float4*)(par + 0);
        *(float4*)&av[4]  = *(const float4*)(par + 4);
        *(float4*)&av[8]  = *(const float4*)(par + 32);
        *(float4*)&av[12] = *(const float4*)(par + 36);
        *(float4*)&bv[0]  = *(const float4*)(pbr + 0);
        *(float4*)&bv[4]  = *(const float4*)(pbr + 4);
        *(float4*)&bv[8]  = *(const float4*)(pbr + 32);
        *(float4*)&bv[12] = *(const float4*)(pbr + 36);

        short8 Ah0, Ah1, Al0, Al1;
#pragma unroll
        for (int i = 0; i < 8; ++i) {
            unsigned short hi, lo;
            splitbf(silu_f(av[i] + bv[i] + rad * w1cr[i]), hi, lo);
            Ah0[i] = (short)hi; Al0[i] = (short)lo;
            splitbf(silu_f(av[8+i] + bv[8+i] + rad * w1cr[8+i]), hi, lo);
            Ah1[i] = (short)hi; Al1[i] = (short)lo;
        }

        f32x4 acc[4];
#pragma unroll
        for (int nt = 0; nt < 4; ++nt) {
            f32x4 a = {0.0f, 0.0f, 0.0f, 0.0f};
            a = __builtin_amdgcn_mfma_f32_16x16x32_bf16(Ah0, Bh[nt*2+0], a, 0, 0, 0);
            a = __builtin_amdgcn_mfma_f32_16x16x32_bf16(Ah1, Bh[nt*2+1], a, 0, 0, 0);
            a = __builtin_amdgcn_mfma_f32_16x16x32_bf16(Ah0, Bl[nt*2+0], a, 0, 0, 0);
            a = __builtin_amdgcn_mfma_f32_16x16x32_bf16(Ah1, Bl[nt*2+1], a, 0, 0, 0);
            a = __builtin_amdgcn_mfma_f32_16x16x32_bf16(Al0, Bh[nt*2+0], a, 0, 0, 0);
            a = __builtin_amdgcn_mfma_f32_16x16x32_bf16(Al1, Bh[nt*2+1], a, 0, 0, 0);
            acc[nt] = a;
        }

        // D row(edge slot) = quad*4+r4, col = nt*16+m16 -> LDS aggregation
#pragma unroll
        for (int r4 = 0; r4 < 4; ++r4) {
            const int rle   = __shfl(rl, quad * 4 + r4);
            const float mke = __shfl(msk, quad * 4 + r4);
            float* ap = &aggld[rle * 64 + m16];
#pragma unroll
            for (int nt = 0; nt < 4; ++nt) {
                float o = silu_f(acc[nt][r4] + b2v[nt]) * mke;
                atomicAdd(ap + nt * 16, o);    // ds_add_f32
            }
        }
    }
    __syncthreads();
    *(float4*)&agg[g * 1024 + tid * 4] = *(const float4*)&aggld[tid * 4];
}

// ---------------- node MLP via MFMA -------------------------------------
__global__ __launch_bounds__(64, 2) void k_node_m(
        float* __restrict__ h, const float* __restrict__ agg,
        const float* __restrict__ h0,
        const float* __restrict__ W1, const float* __restrict__ b1,
        const float* __restrict__ W2, const float* __restrict__ b2) {
    const int lane = threadIdx.x;
    const int quad = lane >> 4, m16 = lane & 15;

    short8 B1h[20], B1l[20];   // [nt*5+kf], k rows 0..159 (pad >=139 with 0)
#pragma unroll
    for (int nt = 0; nt < 4; ++nt) {
#pragma unroll
        for (int kf = 0; kf < 5; ++kf) {
            short8 bh, bl;
#pragma unroll
            for (int j = 0; j < 8; ++j) {
                int row = kf * 32 + quad * 8 + j;
                float w = (row < NIN) ? W1[row * H + nt * 16 + m16] : 0.0f;
                unsigned short hi, lo; splitbf(w, hi, lo);
                bh[j] = (short)hi; bl[j] = (short)lo;
            }
            B1h[nt * 5 + kf] = bh; B1l[nt * 5 + kf] = bl;
        }
    }
    short8 B2h[8], B2l[8];
#pragma unroll
    for (int nt = 0; nt < 4; ++nt) {
#pragma unroll
        for (int kf = 0; kf < 2; ++kf) {
            short8 bh, bl;
#pragma unroll
            for (int j = 0; j < 8; ++j) {
                float w = W2[(kf * 32 + quad * 8 + j) * H + nt * 16 + m16];
                unsigned short hi, lo; splitbf(w, hi, lo);
                bh[j] = (short)hi; bl[j] = (short)lo;
            }
            B2h[nt * 2 + kf] = bh; B2l[nt * 2 + kf] = bl;
        }
    }
    float b1v[4], b2v[4];
#pragma unroll
    for (int nt = 0; nt < 4; ++nt) {
        b1v[nt] = b1[nt * 16 + m16];
        b2v[nt] = b2[nt * 16 + m16];
    }

    __shared__ float tld[16 * 64];

    for (int t = 0; t < 4; ++t) {
        const int nb = (blockIdx.x * 4 + t) * 16;
        float a1[5][8];
        const float* hp = h + (nb + m16) * H + quad * 8;
        const float* ap = agg + (nb + m16) * H + quad * 8;
        *(float4*)&a1[0][0] = *(const float4*)(hp + 0);
        *(float4*)&a1[0][4] = *(const float4*)(hp + 4);
        *(float4*)&a1[1][0] = *(const float4*)(hp + 32);
        *(float4*)&a1[1][4] = *(const float4*)(hp + 36);
        *(float4*)&a1[2][0] = *(const float4*)(ap + 0);
        *(float4*)&a1[2][4] = *(const float4*)(ap + 4);
        *(float4*)&a1[3][0] = *(const float4*)(ap + 32);
        *(float4*)&a1[3][4] = *(const float4*)(ap + 36);
        const float* h0p = h0 + (nb + m16) * F_IN;
#pragma unroll
        for (int j = 0; j < 8; ++j) {
            int kk = quad * 8 + j;
            a1[4][j] = (kk < F_IN) ? h0p[kk] : 0.0f;
        }
        short8 A1h[5], A1l[5];
#pragma unroll
        for (int kf = 0; kf < 5; ++kf) {
            short8 ah, al;
#pragma unroll
            for (int j = 0; j < 8; ++j) {
                unsigned short hi, lo; splitbf(a1[kf][j], hi, lo);
                ah[j] = (short)hi; al[j] = (short)lo;
            }
            A1h[kf] = ah; A1l[kf] = al;
        }
        f32x4 acc[4];
#pragma unroll
        for (int nt = 0; nt < 4; ++nt) {
            f32x4 a = {0.0f, 0.0f, 0.0f, 0.0f};
#pragma unroll
            for (int kf = 0; kf < 5; ++kf)
                a = __builtin_amdgcn_mfma_f32_16x16x32_bf16(A1h[kf], B1h[nt*5+kf], a, 0, 0, 0);
#pragma unroll
            for (int kf = 0; kf < 5; ++kf)
                a = __builtin_amdgcn_mfma_f32_16x16x32_bf16(A1h[kf], B1l[nt*5+kf], a, 0, 0, 0);
#pragma unroll
            for (int kf = 0; kf < 5; ++kf)
                a = __builtin_amdgcn_mfma_f32_16x16x32_bf16(A1l[kf], B1h[nt*5+kf], a, 0, 0, 0);
            acc[nt] = a;
        }
        // t = silu(acc + b1) -> LDS (transpose D-layout -> A-layout)
#pragma unroll
        for (int r4 = 0; r4 < 4; ++r4)
#pragma unroll
            for (int nt = 0; nt < 4; ++nt)
                tld[(quad * 4 + r4) * 64 + nt * 16 + m16] =
                    silu_f(acc[nt][r4] + b1v[nt]);
        __syncthreads();
        float a2[16];
        *(float4*)&a2[0]  = *(const float4*)&tld[m16 * 64 + quad * 8 + 0];
        *(float4*)&a2[4]  = *(const float4*)&tld[m16 * 64 + quad * 8 + 4];
        *(float4*)&a2[8]  = *(const float4*)&tld[m16 * 64 + quad * 8 + 32];
        *(float4*)&a2[12] = *(const float4*)&tld[m16 * 64 + quad * 8 + 36];
        short8 A2h0, A2h1, A2l0, A2l1;
#pragma unroll
        for (int j = 0; j < 8; ++j) {
            unsigned short hi, lo;
            splitbf(a2[j], hi, lo);     A2h0[j] = (short)hi; A2l0[j] = (short)lo;
            splitbf(a2[8+j], hi, lo);   A2h1[j] = (short)hi; A2l1[j] = (short)lo;
        }
        f32x4 acc2[4];
#pragma unroll
        for (int nt = 0; nt < 4; ++nt) {
            f32x4 a = {0.0f, 0.0f, 0.0f, 0.0f};
            a = __builtin_amdgcn_mfma_f32_16x16x32_bf16(A2h0, B2h[nt*2+0], a, 0, 0, 0);
            a = __builtin_amdgcn_mfma_f32_16x16x32_bf16(A2h1, B2h[nt*2+1], a, 0, 0, 0);
            a = __builtin_amdgcn_mfma_f32_16x16x32_bf16(A2h0, B2l[nt*2+0], a, 0, 0, 0);
            a = __builtin_amdgcn_mfma_f32_16x16x32_bf16(A2h1, B2l[nt*2+1], a, 0, 0, 0);
            a = __builtin_amdgcn_mfma_f32_16x16x32_bf16(A2l0, B2h[nt*2+0], a, 0, 0, 0);
            a = __builtin_amdgcn_mfma_f32_16x16x32_bf16(A2l1, B2h[nt*2+1], a, 0, 0, 0);
            acc2[nt] = a;
        }
#pragma unroll
        for (int r4 = 0; r4 < 4; ++r4) {
            const int node = nb + quad * 4 + r4;
#pragma unroll
            for (int nt = 0; nt < 4; ++nt)
                h[node * H + nt * 16 + m16] = acc2[nt][r4] + b2v[nt];
        }
        __syncthreads();
    }
}

// ---------------- node decoder via MFMA ----------------------------------
__global__ __launch_bounds__(64, 2) void k_dec_m(
        float* __restrict__ h, const float* __restrict__ nmask,
        const float* __restrict__ W1, const float* __restrict__ b1,
        const float* __restrict__ W2, const float* __restrict__ b2) {
    const int lane = threadIdx.x;
    const int quad = lane >> 4, m16 = lane & 15;

    short8 B1h[8], B1l[8], B2h[8], B2l[8];
#pragma unroll
    for (int nt = 0; nt < 4; ++nt) {
#pragma unroll
        for (int kf = 0; kf < 2; ++kf) {
            short8 bh1, bl1, bh2, bl2;
#pragma unroll
            for (int j = 0; j < 8; ++j) {
                int row = kf * 32 + quad * 8 + j;
                unsigned short hi, lo;
                splitbf(W1[row * H + nt * 16 + m16], hi, lo);
                bh1[j] = (short)hi; bl1[j] = (short)lo;
                splitbf(W2[row * H + nt * 16 + m16], hi, lo);
                bh2[j] = (short)hi; bl2[j] = (short)lo;
            }
            B1h[nt*2+kf] = bh1; B1l[nt*2+kf] = bl1;
            B2h[nt*2+kf] = bh2; B2l[nt*2+kf] = bl2;
        }
    }
    float b1v[4], b2v[4];
#pragma unroll
    for (int nt = 0; nt < 4; ++nt) {
        b1v[nt] = b1[nt * 16 + m16];
        b2v[nt] = b2[nt * 16 + m16];
    }
    __shared__ float tld[16 * 64];

    for (int t = 0; t < 4; ++t) {
        const int nb = (blockIdx.x * 4 + t) * 16;
        const float* hp = h + (nb + m16) * H + quad * 8;
        float av[16];
        *(float4*)&av[0]  = *(const float4*)(hp + 0);
        *(float4*)&av[4]  = *(const float4*)(hp + 4);
        *(float4*)&av[8]  = *(const float4*)(hp + 32);
        *(float4*)&av[12] = *(const float4*)(hp + 36);
        short8 Ah0, Ah1, Al0, Al1;
#pragma unroll
        for (int j = 0; j < 8; ++j) {
            unsigned short hi, lo;
            splitbf(av[j], hi, lo);     Ah0[j] = (short)hi; Al0[j] = (short)lo;
            splitbf(av[8+j], hi, lo);   Ah1[j] = (short)hi; Al1[j] = (short)lo;
        }
        f32x4 acc[4];
#pragma unroll
        for (int nt = 0; nt < 4; ++nt) {
            f32x4 a = {0.0f, 0.0f, 0.0f, 0.0f};
            a = __builtin_amdgcn_mfma_f32_16x16x32_bf16(Ah0, B1h[nt*2+0], a, 0, 0, 0);
            a = __builtin_amdgcn_mfma_f32_16x16x32_bf16(Ah1, B1h[nt*2+1], a, 0, 0, 0);
            a = __builtin_amdgcn_mfma_f32_16x16x32_bf16(Ah0, B1l[nt*2+0], a, 0, 0, 0);
            a = __builtin_amdgcn_mfma_f32_16x16x32_bf16(Ah1, B1l[nt*2+1], a, 0, 0, 0);
            a = __builtin_amdgcn_mfma_f32_16x16x32_bf16(Al0, B1h[nt*2+0], a, 0, 0, 0);
            a = __builtin_amdgcn_mfma_f32_16x16x32_bf16(Al1, B1h[nt*2+1], a, 0, 0, 0);
            acc[nt] = a;
        }
#pragma unroll
        for (int r4 = 0; r4 < 4; ++r4)
#pragma unroll
            for (int nt = 0; nt < 4; ++nt)
                tld[(quad * 4 + r4) * 64 + nt * 16 + m16] =
                    silu_f(acc[nt][r4] + b1v[nt]);
        __syncthreads();
        float a2[16];
        *(float4*)&a2[0]  = *(const float4*)&tld[m16 * 64 + quad * 8 + 0];
        *(float4*)&a2[4]  = *(const float4*)&tld[m16 * 64 + quad * 8 + 4];
        *(float4*)&a2[8]  = *(const float4*)&tld[m16 * 64 + quad * 8 + 32];
        *(float4*)&a2[12] = *(const float4*)&tld[m16 * 64 + quad * 8 + 36];
        short8 A2h0, A2h1, A2l0, A2l1;
#pragma unroll
        for (int j = 0; j < 8; ++j) {
            unsigned short hi, lo;
            splitbf(a2[j], hi, lo);     A2h0[j] = (short)hi; A2l0[j] = (short)lo;
            splitbf(a2[8+j], hi, lo);   A2h1[j] = (short)hi; A2l1[j] = (short)lo;
        }
        f32x4 acc2[4];
#pragma unroll
        for (int nt = 0; nt < 4; ++nt) {
            f32x4 a = {0.0f, 0.0f, 0.0f, 0.0f};
            a = __builtin_amdgcn_mfma_f32_16x16x32_bf16(A2h0, B2h[nt*2+0], a, 0, 0, 0);
            a = __builtin_amdgcn_mfma_f32_16x16x32_bf16(A2h1, B2h[nt*2+1], a, 0, 0, 0);
            a = __builtin_amdgcn_mfma_f32_16x16x32_bf16(A2h0, B2l[nt*2+0], a, 0, 0, 0);
            a = __builtin_amdgcn_mfma_f32_16x16x32_bf16(A2h1, B2l[nt*2+1], a, 0, 0, 0);
            a = __builtin_amdgcn_mfma_f32_16x16x32_bf16(A2l0, B2h[nt*2+0], a, 0, 0, 0);
            a = __builtin_amdgcn_mfma_f32_16x16x32_bf16(A2l1, B2h[nt*2+1], a, 0, 0, 0);
            acc2[nt] = a;
        }
#pragma unroll
        for (int r4 = 0; r4 < 4; ++r4) {
            const int node = nb + quad * 4 + r4;
            const float nm = nmask[node];
#pragma unroll
            for (int nt = 0; nt < 4; ++nt)
                h[node * H + nt * 16 + m16] = (acc2[nt][r4] + b2v[nt]) * nm;
        }
        __syncthreads();
    }
}

// ---------------- pool + graph decoder + signed reaction aggregation -----
__global__ __launch_bounds__(64) void k_graph(
        const float* __restrict__ h, const int* __restrict__ rid,
        const float* __restrict__ rsign,
        const float* __restrict__ W1, const float* __restrict__ b1,
        const float* __restrict__ W2, const float* __restrict__ b2,
        float* __restrict__ pred) {
    const int g = blockIdx.x;
    const int lane = threadIdx.x;
    float hgv = 0.0f;
#pragma unroll
    for (int m = 0; m < NN_PER_G; ++m)
        hgv += h[(g * NN_PER_G + m) * H + lane];
    __shared__ __align__(16) float hgs[64];
    hgs[lane] = hgv;
    __syncthreads();
    float acc = b1[lane];
#pragma unroll
    for (int k = 0; k < H; ++k)
        acc += hgs[k] * W1[k * H + lane];
    float part = silu_f(acc) * W2[lane];
#pragma unroll
    for (int off = 32; off > 0; off >>= 1)
        part += __shfl_down(part, off);
    if (lane == 0)
        atomAddF(&pred[rid[g]], (part + b2[0]) * rsign[g]);
}

extern "C" void kernel_launch(void* const* d_in, const int* in_sizes, int n_in,
                              void* d_out, int out_size, void* d_ws, size_t ws_size,
                              hipStream_t stream) {
    const float* h0      = (const float*)d_in[0];
    const float* pos     = (const float*)d_in[1];
    const int*   edges   = (const int*)d_in[2];
    const float* nmask   = (const float*)d_in[3];
    const float* emask   = (const float*)d_in[4];
    const int*   rid     = (const int*)d_in[5];
    const float* rsign   = (const float*)d_in[6];
    const float* emb_w   = (const float*)d_in[7];
    const float* emb_b   = (const float*)d_in[8];
    const float* edge_w1 = (const float*)d_in[9];
    const float* edge_b1 = (const float*)d_in[10];
    const float* edge_w2 = (const float*)d_in[11];
    const float* edge_b2 = (const float*)d_in[12];
    const float* node_w1 = (const float*)d_in[13];
    const float* node_b1 = (const float*)d_in[14];
    const float* node_w2 = (const float*)d_in[15];
    const float* node_b2 = (const float*)d_in[16];
    const float* dec_w1  = (const float*)d_in[17];
    const float* dec_b1  = (const float*)d_in[18];
    const float* dec_w2  = (const float*)d_in[19];
    const float* dec_b2  = (const float*)d_in[20];
    const float* g_w1    = (const float*)d_in[21];
    const float* g_b1    = (const float*)d_in[22];
    const float* g_w2    = (const float*)d_in[23];
    const float* g_b2    = (const float*)d_in[24];

    float* h      = (float*)d_ws;            // N*H
    float* agg    = h + N_NODES * H;         // N*H
    float* radial = agg + N_NODES * H;       // E
    float* PA     = radial + N_EDGES;        // N*H
    float* PB     = PA + N_NODES * H;        // N*H
    float* csrR   = PB + N_NODES * H;        // E
    float* csrM   = csrR + N_EDGES;          // E
    int*   csrP   = (int*)(csrM + N_EDGES);  // E
    int*   deg    = csrP + N_EDGES;          // N
    int*   off    = deg + N_NODES;           // N
    int*   bsum   = off + N_NODES;           // 256
    int*   bbase  = bsum + 256;              // 256
    int*   nstart = bbase + 256;             // N+1
    int*   cursor = nstart + N_NODES + 1;    // N
    float* pred   = (float*)d_out;

    hipMemsetAsync(d_out, 0, R_REACT * sizeof(float), stream);
    hipMemsetAsync(deg, 0, N_NODES * sizeof(int), stream);

    k_embed<<<(N_NODES * H) / 256, 256, 0, stream>>>(h0, emb_w, emb_b, h);
    k_radial<<<N_EDGES / 256, 256, 0, stream>>>(edges, pos, radial);
    k_hist<<<N_EDGES / 256, 256, 0, stream>>>(edges, deg);
    k_scan_blk<<<256, 128, 0, stream>>>(deg, off, bsum);
    k_scan_top<<<1, 256, 0, stream>>>(bsum, bbase);
    k_cursor<<<N_NODES / 256, 256, 0, stream>>>(off, bbase, nstart, cursor);
    k_fill<<<N_EDGES / 256, 256, 0, stream>>>(edges, radial, emask, cursor,
                                              csrP, csrR, csrM);

    for (int i = 0; i < L_LAYERS; ++i) {
        k_nodeproj_m<<<N_NODES / 128, 64, 0, stream>>>(
            h, edge_w1 + i * EIN * H, edge_b1 + i * H, PA, PB);
        k_edge5<<<G_GRAPHS, 256, 0, stream>>>(
            PA, PB, nstart, csrP, csrR, csrM,
            edge_w1 + i * EIN * H,
            edge_w2 + i * H * H, edge_b2 + i * H, agg);
        k_node_m<<<N_NODES / 64, 64, 0, stream>>>(
            h, agg, h0,
            node_w1 + i * NIN * H, node_b1 + i * H,
            node_w2 + i * H * H,   node_b2 + i * H);
    }
    k_dec_m<<<N_NODES / 64, 64, 0, stream>>>(h, nmask, dec_w1, dec_b1,
                                             dec_w2, dec_b2);
    k_graph<<<G_GRAPHS, 64, 0, stream>>>(h, rid, rsign, g_w1, g_b1, g_w2,
                                         g_b2, pred);
}

// Round 6
// 809.134 us; speedup vs baseline: 1.4501x; 1.4501x over previous
//
#include <hip/hip_runtime.h>
#include <math.h>

#define N_NODES 32768
#define N_EDGES 491520
#define F_IN    11
#define H       64
#define G_GRAPHS 2048
#define NN_PER_G 16
#define R_REACT 1024
#define L_LAYERS 4
#define EIN     129   // 2H+1
#define NIN     139   // 2H+F
#define NPBLK   32    // nodes per k_edge6 block

typedef __attribute__((ext_vector_type(8))) short short8;
typedef __attribute__((ext_vector_type(4))) float f32x4;

__device__ __forceinline__ float silu_f(float x) {
    return x * __builtin_amdgcn_rcpf(1.0f + __expf(-x));
}
__device__ __forceinline__ void atomAddF(float* p, float v) {
    unsafeAtomicAdd(p, v);
}
__device__ __forceinline__ float bf2f(unsigned short b) {
    union { float f; unsigned u; } v; v.u = ((unsigned)b) << 16;
    return v.f;
}
__device__ __forceinline__ unsigned short f2bf(float x) {   // RNE
    union { float f; unsigned u; } v; v.f = x;
    unsigned r = v.u + 0x7FFFu + ((v.u >> 16) & 1u);
    return (unsigned short)(r >> 16);
}
// RNE split (weights, cold path)
__device__ __forceinline__ void splitbf(float x, unsigned short& hi, unsigned short& lo) {
    hi = f2bf(x);
    lo = f2bf(x - bf2f(hi));
}
// truncation split (hot path; R4-validated absmax 3e-5)
__device__ __forceinline__ void splitbf_t(float x, unsigned short& hi, unsigned short& lo) {
    union { float f; unsigned u; } v; v.f = x;
    hi = (unsigned short)(v.u >> 16);
    union { float f; unsigned u; } w; w.f = x - bf2f(hi);
    lo = (unsigned short)(w.u >> 16);
}

// ---------------- embed ----------------
__global__ __launch_bounds__(256) void k_embed(
        const float* __restrict__ h0, const float* __restrict__ emb_w,
        const float* __restrict__ emb_b, float* __restrict__ h) {
    int tid = blockIdx.x * 256 + threadIdx.x;
    int n = tid >> 6, j = tid & 63;
    float acc = emb_b[j];
#pragma unroll
    for (int k = 0; k < F_IN; ++k)
        acc += h0[n * F_IN + k] * emb_w[k * H + j];
    h[tid] = acc;
}

// ---------------- radial ----------------
__global__ __launch_bounds__(256) void k_radial(
        const int* __restrict__ edges, const float* __restrict__ pos,
        float* __restrict__ radial) {
    int e = blockIdx.x * 256 + threadIdx.x;
    int r = edges[e], c = edges[N_EDGES + e];
    float dx = pos[r * 3 + 0] - pos[c * 3 + 0];
    float dy = pos[r * 3 + 1] - pos[c * 3 + 1];
    float dz = pos[r * 3 + 2] - pos[c * 3 + 2];
    radial[e] = dx * dx + dy * dy + dz * dz;
}

// ---------------- CSR build ----------------
__global__ __launch_bounds__(256) void k_hist(
        const int* __restrict__ edges, int* __restrict__ deg) {
    int e = blockIdx.x * 256 + threadIdx.x;
    atomicAdd(&deg[edges[e]], 1);
}

__global__ __launch_bounds__(128) void k_scan_blk(
        const int* __restrict__ deg, int* __restrict__ off,
        int* __restrict__ bsum) {
    __shared__ int sd[128];
    int b = blockIdx.x;
    sd[threadIdx.x] = deg[b * 128 + threadIdx.x];
    __syncthreads();
    if (threadIdx.x == 0) {
        int s = 0;
        for (int i = 0; i < 128; ++i) { int d = sd[i]; sd[i] = s; s += d; }
        bsum[b] = s;
    }
    __syncthreads();
    off[b * 128 + threadIdx.x] = sd[threadIdx.x];
}

__global__ __launch_bounds__(256) void k_scan_top(
        const int* __restrict__ bsum, int* __restrict__ bbase) {
    __shared__ int sb[256];
    sb[threadIdx.x] = bsum[threadIdx.x];
    __syncthreads();
    if (threadIdx.x == 0) {
        int s = 0;
        for (int i = 0; i < 256; ++i) { int d = sb[i]; sb[i] = s; s += d; }
    }
    __syncthreads();
    bbase[threadIdx.x] = sb[threadIdx.x];
}

__global__ __launch_bounds__(256) void k_cursor(
        const int* __restrict__ off, const int* __restrict__ bbase,
        int* __restrict__ nstart, int* __restrict__ cursor) {
    int n = blockIdx.x * 256 + threadIdx.x;
    int ns = off[n] + bbase[n >> 7];
    nstart[n] = ns;
    cursor[n] = ns;
    if (n == 0) nstart[N_NODES] = N_EDGES;
}

__global__ __launch_bounds__(256) void k_fill(
        const int* __restrict__ edges, const float* __restrict__ radial,
        const float* __restrict__ emask, int* __restrict__ cursor,
        int* __restrict__ csrP, float* __restrict__ csrR,
        float* __restrict__ csrM) {
    int e = blockIdx.x * 256 + threadIdx.x;
    int r = edges[e];
    int pos = atomicAdd(&cursor[r], 1);
    csrP[pos] = edges[N_EDGES + e] | ((r & (NPBLK - 1)) << 16);  // col | row_local
    csrR[pos] = radial[e];
    csrM[pos] = emask[e];
}

// ---------------- node projection via MFMA (1 tile/wave) ----------------
__global__ __launch_bounds__(64, 2) void k_nodeproj_m(
        const float* __restrict__ h, const float* __restrict__ W1,
        const float* __restrict__ b1,
        float* __restrict__ PA, float* __restrict__ PB) {
    const int lane = threadIdx.x;
    const int quad = lane >> 4, m16 = lane & 15;

    short8 Bh[16], Bl[16];     // [nt*2+kf]; nt 0..3 -> PA cols, 4..7 -> PB
#pragma unroll
    for (int nt = 0; nt < 8; ++nt) {
#pragma unroll
        for (int kf = 0; kf < 2; ++kf) {
            short8 bh, bl;
#pragma unroll
            for (int j = 0; j < 8; ++j) {
                int row = (nt >= 4 ? 64 : 0) + kf * 32 + quad * 8 + j;
                float w = W1[row * H + (nt & 3) * 16 + m16];
                unsigned short hi, lo; splitbf(w, hi, lo);
                bh[j] = (short)hi; bl[j] = (short)lo;
            }
            Bh[nt * 2 + kf] = bh; Bl[nt * 2 + kf] = bl;
        }
    }
    float b1v[4];
#pragma unroll
    for (int nt = 0; nt < 4; ++nt) b1v[nt] = b1[nt * 16 + m16];

    const int nb = blockIdx.x * 16;
    const float* hp = h + (nb + m16) * H + quad * 8;
    float av[16];
    *(float4*)&av[0]  = *(const float4*)(hp + 0);
    *(float4*)&av[4]  = *(const float4*)(hp + 4);
    *(float4*)&av[8]  = *(const float4*)(hp + 32);
    *(float4*)&av[12] = *(const float4*)(hp + 36);
    short8 Ah0, Ah1, Al0, Al1;
#pragma unroll
    for (int j = 0; j < 8; ++j) {
        unsigned short hi, lo;
        splitbf_t(av[j], hi, lo);     Ah0[j] = (short)hi; Al0[j] = (short)lo;
        splitbf_t(av[8 + j], hi, lo); Ah1[j] = (short)hi; Al1[j] = (short)lo;
    }
    f32x4 acc[8];
#pragma unroll
    for (int nt = 0; nt < 8; ++nt) {
        f32x4 a = {0.0f, 0.0f, 0.0f, 0.0f};
        a = __builtin_amdgcn_mfma_f32_16x16x32_bf16(Ah0, Bh[nt*2+0], a, 0, 0, 0);
        a = __builtin_amdgcn_mfma_f32_16x16x32_bf16(Ah1, Bh[nt*2+1], a, 0, 0, 0);
        a = __builtin_amdgcn_mfma_f32_16x16x32_bf16(Ah0, Bl[nt*2+0], a, 0, 0, 0);
        a = __builtin_amdgcn_mfma_f32_16x16x32_bf16(Ah1, Bl[nt*2+1], a, 0, 0, 0);
        a = __builtin_amdgcn_mfma_f32_16x16x32_bf16(Al0, Bh[nt*2+0], a, 0, 0, 0);
        a = __builtin_amdgcn_mfma_f32_16x16x32_bf16(Al1, Bh[nt*2+1], a, 0, 0, 0);
        acc[nt] = a;
    }
#pragma unroll
    for (int r4 = 0; r4 < 4; ++r4) {
        const int node = nb + quad * 4 + r4;
#pragma unroll
        for (int nt = 0; nt < 4; ++nt)
            PA[node * H + nt * 16 + m16] = acc[nt][r4] + b1v[nt];
#pragma unroll
        for (int nt = 4; nt < 8; ++nt)
            PB[node * H + (nt - 4) * 16 + m16] = acc[nt][r4];
    }
}

// ---------------- edge MLP: CSR + prefetch + LDS run-reduced agg ---------
// Block owns 32 nodes; 4 waves split its tiles; no global atomics.
__global__ __launch_bounds__(256, 2) void k_edge6(
        const float* __restrict__ PA, const float* __restrict__ PB,
        const int* __restrict__ nstart, const int* __restrict__ csrP,
        const float* __restrict__ csrR, const float* __restrict__ csrM,
        const float* __restrict__ W1,   // only row 128 (w1c) used
        const float* __restrict__ W2, const float* __restrict__ b2,
        float* __restrict__ agg) {
    const int tid = threadIdx.x;
    const int lane = tid & 63, wave = tid >> 6;
    const int quad = lane >> 4, m16 = lane & 15;
    const int n0 = blockIdx.x * NPBLK;

    __shared__ float aggld[NPBLK * 68];   // stride 68: 16B-aligned rows, bank spread
    for (int i = tid; i < NPBLK * 68; i += 256) aggld[i] = 0.0f;

    short8 Bh[8], Bl[8];             // W2 frags [nt*2+kf]
#pragma unroll
    for (int nt = 0; nt < 4; ++nt) {
#pragma unroll
        for (int kf = 0; kf < 2; ++kf) {
            short8 bh, bl;
#pragma unroll
            for (int j = 0; j < 8; ++j) {
                float w = W2[(kf * 32 + quad * 8 + j) * H + nt * 16 + m16];
                unsigned short hi, lo; splitbf(w, hi, lo);
                bh[j] = (short)hi; bl[j] = (short)lo;
            }
            Bh[nt * 2 + kf] = bh; Bl[nt * 2 + kf] = bl;
        }
    }
    float w1cr[16];
#pragma unroll
    for (int i = 0; i < 16; ++i) {
        int k = (i < 8) ? (quad * 8 + i) : (32 + quad * 8 + (i - 8));
        w1cr[i] = W1[128 * H + k];
    }
    float b2v[4];
#pragma unroll
    for (int nt = 0; nt < 4; ++nt) b2v[nt] = b2[nt * 16 + m16];

    const int start = nstart[n0];
    const int end   = nstart[n0 + NPBLK];
    __syncthreads();

    const int ntiles = (end - start + 15) >> 4;

    // -------- stage A regs --------
    float radA = 0.0f, avA[16], bvA[16];
    int rlA = 0;                    // this lane's A-row local dest
    int rlqA[4]; float mkqA[4];     // per-quad epilogue meta

    int t = wave;
    bool haveA = t < ntiles;
    if (haveA) {
        const int idx = start + t * 16 + m16;
        const int ss = min(idx, N_EDGES - 1);
        const int pk = csrP[ss];
        radA = csrR[ss];
        const int c = pk & 0xFFFF;
        rlA = pk >> 16;
        const int sb = start + t * 16 + quad * 4;
#pragma unroll
        for (int r4 = 0; r4 < 4; ++r4) {
            int s = sb + r4, s2 = min(s, N_EDGES - 1);
            rlqA[r4] = csrP[s2] >> 16;
            mkqA[r4] = (s < end) ? csrM[s2] : 0.0f;
        }
        const float* par = PA + (n0 + rlA) * H + quad * 8;
        const float* pbr = PB + c * H + quad * 8;
        *(float4*)&avA[0]  = *(const float4*)(par + 0);
        *(float4*)&avA[4]  = *(const float4*)(par + 4);
        *(float4*)&avA[8]  = *(const float4*)(par + 32);
        *(float4*)&avA[12] = *(const float4*)(par + 36);
        *(float4*)&bvA[0]  = *(const float4*)(pbr + 0);
        *(float4*)&bvA[4]  = *(const float4*)(pbr + 4);
        *(float4*)&bvA[8]  = *(const float4*)(pbr + 32);
        *(float4*)&bvA[12] = *(const float4*)(pbr + 36);
    }

    while (haveA) {
        const int tn = t + 4;
        const bool haveB = tn < ntiles;
        float radB = 0.0f, bvB[16];
        int rlB = 0;
        int rlqB[4]; float mkqB[4];
        if (haveB) {
            const int idx = start + tn * 16 + m16;
            const int ss = min(idx, N_EDGES - 1);
            const int pk = csrP[ss];
            radB = csrR[ss];
            const int c = pk & 0xFFFF;
            rlB = pk >> 16;
            const int sb = start + tn * 16 + quad * 4;
#pragma unroll
            for (int r4 = 0; r4 < 4; ++r4) {
                int s = sb + r4, s2 = min(s, N_EDGES - 1);
                rlqB[r4] = csrP[s2] >> 16;
                mkqB[r4] = (s < end) ? csrM[s2] : 0.0f;
            }
            const float* pbr = PB + c * H + quad * 8;
            *(float4*)&bvB[0]  = *(const float4*)(pbr + 0);
            *(float4*)&bvB[4]  = *(const float4*)(pbr + 4);
            *(float4*)&bvB[8]  = *(const float4*)(pbr + 32);
            *(float4*)&bvB[12] = *(const float4*)(pbr + 36);
        }

        // ---- compute tile t ----
        short8 Ah0, Ah1, Al0, Al1;
#pragma unroll
        for (int i = 0; i < 8; ++i) {
            unsigned short hi, lo;
            splitbf_t(silu_f(avA[i] + bvA[i] + radA * w1cr[i]), hi, lo);
            Ah0[i] = (short)hi; Al0[i] = (short)lo;
            splitbf_t(silu_f(avA[8+i] + bvA[8+i] + radA * w1cr[8+i]), hi, lo);
            Ah1[i] = (short)hi; Al1[i] = (short)lo;
        }
        f32x4 acc[4];
#pragma unroll
        for (int nt = 0; nt < 4; ++nt) {
            f32x4 a = {0.0f, 0.0f, 0.0f, 0.0f};
            a = __builtin_amdgcn_mfma_f32_16x16x32_bf16(Ah0, Bh[nt*2+0], a, 0, 0, 0);
            a = __builtin_amdgcn_mfma_f32_16x16x32_bf16(Ah1, Bh[nt*2+1], a, 0, 0, 0);
            a = __builtin_amdgcn_mfma_f32_16x16x32_bf16(Ah0, Bl[nt*2+0], a, 0, 0, 0);
            a = __builtin_amdgcn_mfma_f32_16x16x32_bf16(Ah1, Bl[nt*2+1], a, 0, 0, 0);
            a = __builtin_amdgcn_mfma_f32_16x16x32_bf16(Al0, Bh[nt*2+0], a, 0, 0, 0);
            a = __builtin_amdgcn_mfma_f32_16x16x32_bf16(Al1, Bh[nt*2+1], a, 0, 0, 0);
            acc[nt] = a;
        }

        // ---- epilogue: run-length reduce over D-rows, then LDS atomic ----
#pragma unroll
        for (int nt = 0; nt < 4; ++nt) {
            float oo[4];
#pragma unroll
            for (int r4 = 0; r4 < 4; ++r4)
                oo[r4] = silu_f(acc[nt][r4] + b2v[nt]) * mkqA[r4];
            int cur = rlqA[0]; float s = oo[0];
#pragma unroll
            for (int r4 = 1; r4 < 4; ++r4) {
                if (rlqA[r4] == cur) { s += oo[r4]; }
                else {
                    atomicAdd(&aggld[cur * 68 + nt * 16 + m16], s);
                    cur = rlqA[r4]; s = oo[r4];
                }
            }
            atomicAdd(&aggld[cur * 68 + nt * 16 + m16], s);
        }

        // ---- rotate ----
        if (haveB) {
            radA = radB; rlA = rlB;
#pragma unroll
            for (int r4 = 0; r4 < 4; ++r4) { rlqA[r4] = rlqB[r4]; mkqA[r4] = mkqB[r4]; }
            const float* par = PA + (n0 + rlA) * H + quad * 8;
            *(float4*)&avA[0]  = *(const float4*)(par + 0);
            *(float4*)&avA[4]  = *(const float4*)(par + 4);
            *(float4*)&avA[8]  = *(const float4*)(par + 32);
            *(float4*)&avA[12] = *(const float4*)(par + 36);
#pragma unroll
            for (int i = 0; i < 16; ++i) bvA[i] = bvB[i];
        }
        t = tn; haveA = haveB;
    }

    __syncthreads();
#pragma unroll
    for (int i = tid; i < NPBLK * 16; i += 256) {
        int n = i >> 4, cb = (i & 15) << 2;
        *(float4*)&agg[(n0 + n) * H + cb] = *(const float4*)&aggld[n * 68 + cb];
    }
}

// ---------------- node MLP via MFMA (1 tile/wave) ------------------------
__global__ __launch_bounds__(64, 2) void k_node_m(
        float* __restrict__ h, const float* __restrict__ agg,
        const float* __restrict__ h0,
        const float* __restrict__ W1, const float* __restrict__ b1,
        const float* __restrict__ W2, const float* __restrict__ b2) {
    const int lane = threadIdx.x;
    const int quad = lane >> 4, m16 = lane & 15;

    short8 B1h[20], B1l[20];   // [nt*5+kf], rows 0..159 (pad >=139 with 0)
#pragma unroll
    for (int nt = 0; nt < 4; ++nt) {
#pragma unroll
        for (int kf = 0; kf < 5; ++kf) {
            short8 bh, bl;
#pragma unroll
            for (int j = 0; j < 8; ++j) {
                int row = kf * 32 + quad * 8 + j;
                float w = (row < NIN) ? W1[row * H + nt * 16 + m16] : 0.0f;
                unsigned short hi, lo; splitbf(w, hi, lo);
                bh[j] = (short)hi; bl[j] = (short)lo;
            }
            B1h[nt * 5 + kf] = bh; B1l[nt * 5 + kf] = bl;
        }
    }
    short8 B2h[8], B2l[8];
#pragma unroll
    for (int nt = 0; nt < 4; ++nt) {
#pragma unroll
        for (int kf = 0; kf < 2; ++kf) {
            short8 bh, bl;
#pragma unroll
            for (int j = 0; j < 8; ++j) {
                float w = W2[(kf * 32 + quad * 8 + j) * H + nt * 16 + m16];
                unsigned short hi, lo; splitbf(w, hi, lo);
                bh[j] = (short)hi; bl[j] = (short)lo;
            }
            B2h[nt * 2 + kf] = bh; B2l[nt * 2 + kf] = bl;
        }
    }
    float b1v[4], b2v[4];
#pragma unroll
    for (int nt = 0; nt < 4; ++nt) {
        b1v[nt] = b1[nt * 16 + m16];
        b2v[nt] = b2[nt * 16 + m16];
    }

    __shared__ float tld[16 * 64];

    const int nb = blockIdx.x * 16;
    float a1[5][8];
    const float* hp = h + (nb + m16) * H + quad * 8;
    const float* ap = agg + (nb + m16) * H + quad * 8;
    *(float4*)&a1[0][0] = *(const float4*)(hp + 0);
    *(float4*)&a1[0][4] = *(const float4*)(hp + 4);
    *(float4*)&a1[1][0] = *(const float4*)(hp + 32);
    *(float4*)&a1[1][4] = *(const float4*)(hp + 36);
    *(float4*)&a1[2][0] = *(const float4*)(ap + 0);
    *(float4*)&a1[2][4] = *(const float4*)(ap + 4);
    *(float4*)&a1[3][0] = *(const float4*)(ap + 32);
    *(float4*)&a1[3][4] = *(const float4*)(ap + 36);
    const float* h0p = h0 + (nb + m16) * F_IN;
#pragma unroll
    for (int j = 0; j < 8; ++j) {
        int kk = quad * 8 + j;
        a1[4][j] = (kk < F_IN) ? h0p[kk] : 0.0f;
    }
    short8 A1h[5], A1l[5];
#pragma unroll
    for (int kf = 0; kf < 5; ++kf) {
        short8 ah, al;
#pragma unroll
        for (int j = 0; j < 8; ++j) {
            unsigned short hi, lo; splitbf_t(a1[kf][j], hi, lo);
            ah[j] = (short)hi; al[j] = (short)lo;
        }
        A1h[kf] = ah; A1l[kf] = al;
    }
    f32x4 acc[4];
#pragma unroll
    for (int nt = 0; nt < 4; ++nt) {
        f32x4 a = {0.0f, 0.0f, 0.0f, 0.0f};
#pragma unroll
        for (int kf = 0; kf < 5; ++kf)
            a = __builtin_amdgcn_mfma_f32_16x16x32_bf16(A1h[kf], B1h[nt*5+kf], a, 0, 0, 0);
#pragma unroll
        for (int kf = 0; kf < 5; ++kf)
            a = __builtin_amdgcn_mfma_f32_16x16x32_bf16(A1h[kf], B1l[nt*5+kf], a, 0, 0, 0);
#pragma unroll
        for (int kf = 0; kf < 5; ++kf)
            a = __builtin_amdgcn_mfma_f32_16x16x32_bf16(A1l[kf], B1h[nt*5+kf], a, 0, 0, 0);
        acc[nt] = a;
    }
#pragma unroll
    for (int r4 = 0; r4 < 4; ++r4)
#pragma unroll
        for (int nt = 0; nt < 4; ++nt)
            tld[(quad * 4 + r4) * 64 + nt * 16 + m16] =
                silu_f(acc[nt][r4] + b1v[nt]);
    __syncthreads();
    float a2[16];
    *(float4*)&a2[0]  = *(const float4*)&tld[m16 * 64 + quad * 8 + 0];
    *(float4*)&a2[4]  = *(const float4*)&tld[m16 * 64 + quad * 8 + 4];
    *(float4*)&a2[8]  = *(const float4*)&tld[m16 * 64 + quad * 8 + 32];
    *(float4*)&a2[12] = *(const float4*)&tld[m16 * 64 + quad * 8 + 36];
    short8 A2h0, A2h1, A2l0, A2l1;
#pragma unroll
    for (int j = 0; j < 8; ++j) {
        unsigned short hi, lo;
        splitbf_t(a2[j], hi, lo);     A2h0[j] = (short)hi; A2l0[j] = (short)lo;
        splitbf_t(a2[8+j], hi, lo);   A2h1[j] = (short)hi; A2l1[j] = (short)lo;
    }
    f32x4 acc2[4];
#pragma unroll
    for (int nt = 0; nt < 4; ++nt) {
        f32x4 a = {0.0f, 0.0f, 0.0f, 0.0f};
        a = __builtin_amdgcn_mfma_f32_16x16x32_bf16(A2h0, B2h[nt*2+0], a, 0, 0, 0);
        a = __builtin_amdgcn_mfma_f32_16x16x32_bf16(A2h1, B2h[nt*2+1], a, 0, 0, 0);
        a = __builtin_amdgcn_mfma_f32_16x16x32_bf16(A2h0, B2l[nt*2+0], a, 0, 0, 0);
        a = __builtin_amdgcn_mfma_f32_16x16x32_bf16(A2h1, B2l[nt*2+1], a, 0, 0, 0);
        a = __builtin_amdgcn_mfma_f32_16x16x32_bf16(A2l0, B2h[nt*2+0], a, 0, 0, 0);
        a = __builtin_amdgcn_mfma_f32_16x16x32_bf16(A2l1, B2h[nt*2+1], a, 0, 0, 0);
        acc2[nt] = a;
    }
#pragma unroll
    for (int r4 = 0; r4 < 4; ++r4) {
        const int node = nb + quad * 4 + r4;
#pragma unroll
        for (int nt = 0; nt < 4; ++nt)
            h[node * H + nt * 16 + m16] = acc2[nt][r4] + b2v[nt];
    }
}

// ---------------- node decoder via MFMA (1 tile/wave) --------------------
__global__ __launch_bounds__(64, 2) void k_dec_m(
        float* __restrict__ h, const float* __restrict__ nmask,
        const float* __restrict__ W1, const float* __restrict__ b1,
        const float* __restrict__ W2, const float* __restrict__ b2) {
    const int lane = threadIdx.x;
    const int quad = lane >> 4, m16 = lane & 15;

    short8 B1h[8], B1l[8], B2h[8], B2l[8];
#pragma unroll
    for (int nt = 0; nt < 4; ++nt) {
#pragma unroll
        for (int kf = 0; kf < 2; ++kf) {
            short8 bh1, bl1, bh2, bl2;
#pragma unroll
            for (int j = 0; j < 8; ++j) {
                int row = kf * 32 + quad * 8 + j;
                unsigned short hi, lo;
                splitbf(W1[row * H + nt * 16 + m16], hi, lo);
                bh1[j] = (short)hi; bl1[j] = (short)lo;
                splitbf(W2[row * H + nt * 16 + m16], hi, lo);
                bh2[j] = (short)hi; bl2[j] = (short)lo;
            }
            B1h[nt*2+kf] = bh1; B1l[nt*2+kf] = bl1;
            B2h[nt*2+kf] = bh2; B2l[nt*2+kf] = bl2;
        }
    }
    float b1v[4], b2v[4];
#pragma unroll
    for (int nt = 0; nt < 4; ++nt) {
        b1v[nt] = b1[nt * 16 + m16];
        b2v[nt] = b2[nt * 16 + m16];
    }
    __shared__ float tld[16 * 64];

    const int nb = blockIdx.x * 16;
    const float* hp = h + (nb + m16) * H + quad * 8;
    float av[16];
    *(float4*)&av[0]  = *(const float4*)(hp + 0);
    *(float4*)&av[4]  = *(const float4*)(hp + 4);
    *(float4*)&av[8]  = *(const float4*)(hp + 32);
    *(float4*)&av[12] = *(const float4*)(hp + 36);
    short8 Ah0, Ah1, Al0, Al1;
#pragma unroll
    for (int j = 0; j < 8; ++j) {
        unsigned short hi, lo;
        splitbf_t(av[j], hi, lo);     Ah0[j] = (short)hi; Al0[j] = (short)lo;
        splitbf_t(av[8+j], hi, lo);   Ah1[j] = (short)hi; Al1[j] = (short)lo;
    }
    f32x4 acc[4];
#pragma unroll
    for (int nt = 0; nt < 4; ++nt) {
        f32x4 a = {0.0f, 0.0f, 0.0f, 0.0f};
        a = __builtin_amdgcn_mfma_f32_16x16x32_bf16(Ah0, B1h[nt*2+0], a, 0, 0, 0);
        a = __builtin_amdgcn_mfma_f32_16x16x32_bf16(Ah1, B1h[nt*2+1], a, 0, 0, 0);
        a = __builtin_amdgcn_mfma_f32_16x16x32_bf16(Ah0, B1l[nt*2+0], a, 0, 0, 0);
        a = __builtin_amdgcn_mfma_f32_16x16x32_bf16(Ah1, B1l[nt*2+1], a, 0, 0, 0);
        a = __builtin_amdgcn_mfma_f32_16x16x32_bf16(Al0, B1h[nt*2+0], a, 0, 0, 0);
        a = __builtin_amdgcn_mfma_f32_16x16x32_bf16(Al1, B1h[nt*2+1], a, 0, 0, 0);
        acc[nt] = a;
    }
#pragma unroll
    for (int r4 = 0; r4 < 4; ++r4)
#pragma unroll
        for (int nt = 0; nt < 4; ++nt)
            tld[(quad * 4 + r4) * 64 + nt * 16 + m16] =
                silu_f(acc[nt][r4] + b1v[nt]);
    __syncthreads();
    float a2[16];
    *(float4*)&a2[0]  = *(const float4*)&tld[m16 * 64 + quad * 8 + 0];
    *(float4*)&a2[4]  = *(const float4*)&tld[m16 * 64 + quad * 8 + 4];
    *(float4*)&a2[8]  = *(const float4*)&tld[m16 * 64 + quad * 8 + 32];
    *(float4*)&a2[12] = *(const float4*)&tld[m16 * 64 + quad * 8 + 36];
    short8 A2h0, A2h1, A2l0, A2l1;
#pragma unroll
    for (int j = 0; j < 8; ++j) {
        unsigned short hi, lo;
        splitbf_t(a2[j], hi, lo);     A2h0[j] = (short)hi; A2l0[j] = (short)lo;
        splitbf_t(a2[8+j], hi, lo);   A2h1[j] = (short)hi; A2l1[j] = (short)lo;
    }
    f32x4 acc2[4];
#pragma unroll
    for (int nt = 0; nt < 4; ++nt) {
        f32x4 a = {0.0f, 0.0f, 0.0f, 0.0f};
        a = __builtin_amdgcn_mfma_f32_16x16x32_bf16(A2h0, B2h[nt*2+0], a, 0, 0, 0);
        a = __builtin_amdgcn_mfma_f32_16x16x32_bf16(A2h1, B2h[nt*2+1], a, 0, 0, 0);
        a = __builtin_amdgcn_mfma_f32_16x16x32_bf16(A2h0, B2l[nt*2+0], a, 0, 0, 0);
        a = __builtin_amdgcn_mfma_f32_16x16x32_bf16(A2h1, B2l[nt*2+1], a, 0, 0, 0);
        a = __builtin_amdgcn_mfma_f32_16x16x32_bf16(A2l0, B2h[nt*2+0], a, 0, 0, 0);
        a = __builtin_amdgcn_mfma_f32_16x16x32_bf16(A2l1, B2h[nt*2+1], a, 0, 0, 0);
        acc2[nt] = a;
    }
#pragma unroll
    for (int r4 = 0; r4 < 4; ++r4) {
        const int node = nb + quad * 4 + r4;
        const float nm = nmask[node];
#pragma unroll
        for (int nt = 0; nt < 4; ++nt)
            h[node * H + nt * 16 + m16] = (acc2[nt][r4] + b2v[nt]) * nm;
    }
}

// ---------------- pool + graph decoder + reaction aggregation ------------
__global__ __launch_bounds__(64) void k_graph(
        const float* __restrict__ h, const int* __restrict__ rid,
        const float* __restrict__ rsign,
        const float* __restrict__ W1, const float* __restrict__ b1,
        const float* __restrict__ W2, const float* __restrict__ b2,
        float* __restrict__ pred) {
    const int g = blockIdx.x;
    const int lane = threadIdx.x;
    float hgv = 0.0f;
#pragma unroll
    for (int m = 0; m < NN_PER_G; ++m)
        hgv += h[(g * NN_PER_G + m) * H + lane];
    __shared__ __align__(16) float hgs[64];
    hgs[lane] = hgv;
    __syncthreads();
    float acc = b1[lane];
#pragma unroll
    for (int k = 0; k < H; ++k)
        acc += hgs[k] * W1[k * H + lane];
    float part = silu_f(acc) * W2[lane];
#pragma unroll
    for (int off = 32; off > 0; off >>= 1)
        part += __shfl_down(part, off);
    if (lane == 0)
        atomAddF(&pred[rid[g]], (part + b2[0]) * rsign[g]);
}

extern "C" void kernel_launch(void* const* d_in, const int* in_sizes, int n_in,
                              void* d_out, int out_size, void* d_ws, size_t ws_size,
                              hipStream_t stream) {
    const float* h0      = (const float*)d_in[0];
    const float* pos     = (const float*)d_in[1];
    const int*   edges   = (const int*)d_in[2];
    const float* nmask   = (const float*)d_in[3];
    const float* emask   = (const float*)d_in[4];
    const int*   rid     = (const int*)d_in[5];
    const float* rsign   = (const float*)d_in[6];
    const float* emb_w   = (const float*)d_in[7];
    const float* emb_b   = (const float*)d_in[8];
    const float* edge_w1 = (const float*)d_in[9];
    const float* edge_b1 = (const float*)d_in[10];
    const float* edge_w2 = (const float*)d_in[11];
    const float* edge_b2 = (const float*)d_in[12];
    const float* node_w1 = (const float*)d_in[13];
    const float* node_b1 = (const float*)d_in[14];
    const float* node_w2 = (const float*)d_in[15];
    const float* node_b2 = (const float*)d_in[16];
    const float* dec_w1  = (const float*)d_in[17];
    const float* dec_b1  = (const float*)d_in[18];
    const float* dec_w2  = (const float*)d_in[19];
    const float* dec_b2  = (const float*)d_in[20];
    const float* g_w1    = (const float*)d_in[21];
    const float* g_b1    = (const float*)d_in[22];
    const float* g_w2    = (const float*)d_in[23];
    const float* g_b2    = (const float*)d_in[24];

    float* h      = (float*)d_ws;            // N*H
    float* agg    = h + N_NODES * H;         // N*H
    float* radial = agg + N_NODES * H;       // E
    float* PA     = radial + N_EDGES;        // N*H
    float* PB     = PA + N_NODES * H;        // N*H
    float* csrR   = PB + N_NODES * H;        // E
    float* csrM   = csrR + N_EDGES;          // E
    int*   csrP   = (int*)(csrM + N_EDGES);  // E
    int*   deg    = csrP + N_EDGES;          // N
    int*   off    = deg + N_NODES;           // N
    int*   bsum   = off + N_NODES;           // 256
    int*   bbase  = bsum + 256;              // 256
    int*   nstart = bbase + 256;             // N+1
    int*   cursor = nstart + N_NODES + 1;    // N
    float* pred   = (float*)d_out;

    hipMemsetAsync(d_out, 0, R_REACT * sizeof(float), stream);
    hipMemsetAsync(deg, 0, N_NODES * sizeof(int), stream);

    k_embed<<<(N_NODES * H) / 256, 256, 0, stream>>>(h0, emb_w, emb_b, h);
    k_radial<<<N_EDGES / 256, 256, 0, stream>>>(edges, pos, radial);
    k_hist<<<N_EDGES / 256, 256, 0, stream>>>(edges, deg);
    k_scan_blk<<<256, 128, 0, stream>>>(deg, off, bsum);
    k_scan_top<<<1, 256, 0, stream>>>(bsum, bbase);
    k_cursor<<<N_NODES / 256, 256, 0, stream>>>(off, bbase, nstart, cursor);
    k_fill<<<N_EDGES / 256, 256, 0, stream>>>(edges, radial, emask, cursor,
                                              csrP, csrR, csrM);

    for (int i = 0; i < L_LAYERS; ++i) {
        k_nodeproj_m<<<N_NODES / 16, 64, 0, stream>>>(
            h, edge_w1 + i * EIN * H, edge_b1 + i * H, PA, PB);
        k_edge6<<<N_NODES / NPBLK, 256, 0, stream>>>(
            PA, PB, nstart, csrP, csrR, csrM,
            edge_w1 + i * EIN * H,
            edge_w2 + i * H * H, edge_b2 + i * H, agg);
        k_node_m<<<N_NODES / 16, 64, 0, stream>>>(
            h, agg, h0,
            node_w1 + i * NIN * H, node_b1 + i * H,
            node_w2 + i * H * H,   node_b2 + i * H);
    }
    k_dec_m<<<N_NODES / 16, 64, 0, stream>>>(h, nmask, dec_w1, dec_b1,
                                             dec_w2, dec_b2);
    k_graph<<<G_GRAPHS, 64, 0, stream>>>(h, rid, rsign, g_w1, g_b1, g_w2,
                                         g_b2, pred);
}

// Round 7
// 561.237 us; speedup vs baseline: 2.0906x; 1.4417x over previous
//
#include <hip/hip_runtime.h>
#include <math.h>

#define N_NODES 32768
#define N_EDGES 491520
#define F_IN    11
#define H       64
#define G_GRAPHS 2048
#define NN_PER_G 16
#define R_REACT 1024
#define L_LAYERS 4
#define EIN     129   // 2H+1
#define NIN     139   // 2H+F
#define NPBLK   32    // nodes per k_edge6 block

typedef __attribute__((ext_vector_type(8))) short short8;
typedef __attribute__((ext_vector_type(4))) float f32x4;

__device__ __forceinline__ float silu_f(float x) {
    return x * __builtin_amdgcn_rcpf(1.0f + __expf(-x));
}
__device__ __forceinline__ void atomAddF(float* p, float v) {
    unsafeAtomicAdd(p, v);
}
__device__ __forceinline__ float bf2f(unsigned short b) {
    union { float f; unsigned u; } v; v.u = ((unsigned)b) << 16;
    return v.f;
}
__device__ __forceinline__ unsigned short f2bf(float x) {   // RNE
    union { float f; unsigned u; } v; v.f = x;
    unsigned r = v.u + 0x7FFFu + ((v.u >> 16) & 1u);
    return (unsigned short)(r >> 16);
}
// RNE split (weights, cold path)
__device__ __forceinline__ void splitbf(float x, unsigned short& hi, unsigned short& lo) {
    hi = f2bf(x);
    lo = f2bf(x - bf2f(hi));
}
// truncation split (hot path; R4-validated absmax 3e-5)
__device__ __forceinline__ void splitbf_t(float x, unsigned short& hi, unsigned short& lo) {
    union { float f; unsigned u; } v; v.f = x;
    hi = (unsigned short)(v.u >> 16);
    union { float f; unsigned u; } w; w.f = x - bf2f(hi);
    lo = (unsigned short)(w.u >> 16);
}

// ---------------- embed ----------------
__global__ __launch_bounds__(256) void k_embed(
        const float* __restrict__ h0, const float* __restrict__ emb_w,
        const float* __restrict__ emb_b, float* __restrict__ h) {
    int tid = blockIdx.x * 256 + threadIdx.x;
    int n = tid >> 6, j = tid & 63;
    float acc = emb_b[j];
#pragma unroll
    for (int k = 0; k < F_IN; ++k)
        acc += h0[n * F_IN + k] * emb_w[k * H + j];
    h[tid] = acc;
}

// ---------------- radial ----------------
__global__ __launch_bounds__(256) void k_radial(
        const int* __restrict__ edges, const float* __restrict__ pos,
        float* __restrict__ radial) {
    int e = blockIdx.x * 256 + threadIdx.x;
    int r = edges[e], c = edges[N_EDGES + e];
    float dx = pos[r * 3 + 0] - pos[c * 3 + 0];
    float dy = pos[r * 3 + 1] - pos[c * 3 + 1];
    float dz = pos[r * 3 + 2] - pos[c * 3 + 2];
    radial[e] = dx * dx + dy * dy + dz * dz;
}

// ---------------- CSR build ----------------
__global__ __launch_bounds__(256) void k_hist(
        const int* __restrict__ edges, int* __restrict__ deg) {
    int e = blockIdx.x * 256 + threadIdx.x;
    atomicAdd(&deg[edges[e]], 1);
}

__global__ __launch_bounds__(128) void k_scan_blk(
        const int* __restrict__ deg, int* __restrict__ off,
        int* __restrict__ bsum) {
    __shared__ int sd[128];
    int b = blockIdx.x;
    sd[threadIdx.x] = deg[b * 128 + threadIdx.x];
    __syncthreads();
    if (threadIdx.x == 0) {
        int s = 0;
        for (int i = 0; i < 128; ++i) { int d = sd[i]; sd[i] = s; s += d; }
        bsum[b] = s;
    }
    __syncthreads();
    off[b * 128 + threadIdx.x] = sd[threadIdx.x];
}

__global__ __launch_bounds__(256) void k_scan_top(
        const int* __restrict__ bsum, int* __restrict__ bbase) {
    __shared__ int sb[256];
    sb[threadIdx.x] = bsum[threadIdx.x];
    __syncthreads();
    if (threadIdx.x == 0) {
        int s = 0;
        for (int i = 0; i < 256; ++i) { int d = sb[i]; sb[i] = s; s += d; }
    }
    __syncthreads();
    bbase[threadIdx.x] = sb[threadIdx.x];
}

__global__ __launch_bounds__(256) void k_cursor(
        const int* __restrict__ off, const int* __restrict__ bbase,
        int* __restrict__ nstart, int* __restrict__ cursor) {
    int n = blockIdx.x * 256 + threadIdx.x;
    int ns = off[n] + bbase[n >> 7];
    nstart[n] = ns;
    cursor[n] = ns;
    if (n == 0) nstart[N_NODES] = N_EDGES;
}

__global__ __launch_bounds__(256) void k_fill(
        const int* __restrict__ edges, const float* __restrict__ radial,
        const float* __restrict__ emask, int* __restrict__ cursor,
        int* __restrict__ csrP, float* __restrict__ csrR,
        float* __restrict__ csrM) {
    int e = blockIdx.x * 256 + threadIdx.x;
    int r = edges[e];
    int pos = atomicAdd(&cursor[r], 1);
    csrP[pos] = edges[N_EDGES + e] | ((r & (NPBLK - 1)) << 16);  // col | row_local
    csrR[pos] = radial[e];
    csrM[pos] = emask[e];
}

// ---------------- node projection via MFMA (2 tiles/wave, no spill) ------
__global__ __launch_bounds__(64, 1) void k_nodeproj_m(
        const float* __restrict__ h, const float* __restrict__ W1,
        const float* __restrict__ b1,
        float* __restrict__ PA, float* __restrict__ PB) {
    const int lane = threadIdx.x;
    const int quad = lane >> 4, m16 = lane & 15;

    short8 Bh[16], Bl[16];     // [nt*2+kf]; nt 0..3 -> PA cols, 4..7 -> PB
#pragma unroll
    for (int nt = 0; nt < 8; ++nt) {
#pragma unroll
        for (int kf = 0; kf < 2; ++kf) {
            short8 bh, bl;
#pragma unroll
            for (int j = 0; j < 8; ++j) {
                int row = (nt >= 4 ? 64 : 0) + kf * 32 + quad * 8 + j;
                float w = W1[row * H + (nt & 3) * 16 + m16];
                unsigned short hi, lo; splitbf(w, hi, lo);
                bh[j] = (short)hi; bl[j] = (short)lo;
            }
            Bh[nt * 2 + kf] = bh; Bl[nt * 2 + kf] = bl;
        }
    }
    float b1v[4];
#pragma unroll
    for (int nt = 0; nt < 4; ++nt) b1v[nt] = b1[nt * 16 + m16];

    for (int t = 0; t < 2; ++t) {
        const int nb = (blockIdx.x * 2 + t) * 16;
        const float* hp = h + (nb + m16) * H + quad * 8;
        float av[16];
        *(float4*)&av[0]  = *(const float4*)(hp + 0);
        *(float4*)&av[4]  = *(const float4*)(hp + 4);
        *(float4*)&av[8]  = *(const float4*)(hp + 32);
        *(float4*)&av[12] = *(const float4*)(hp + 36);
        short8 Ah0, Ah1, Al0, Al1;
#pragma unroll
        for (int j = 0; j < 8; ++j) {
            unsigned short hi, lo;
            splitbf_t(av[j], hi, lo);     Ah0[j] = (short)hi; Al0[j] = (short)lo;
            splitbf_t(av[8 + j], hi, lo); Ah1[j] = (short)hi; Al1[j] = (short)lo;
        }
        f32x4 acc[8];
#pragma unroll
        for (int nt = 0; nt < 8; ++nt) {
            f32x4 a = {0.0f, 0.0f, 0.0f, 0.0f};
            a = __builtin_amdgcn_mfma_f32_16x16x32_bf16(Ah0, Bh[nt*2+0], a, 0, 0, 0);
            a = __builtin_amdgcn_mfma_f32_16x16x32_bf16(Ah1, Bh[nt*2+1], a, 0, 0, 0);
            a = __builtin_amdgcn_mfma_f32_16x16x32_bf16(Ah0, Bl[nt*2+0], a, 0, 0, 0);
            a = __builtin_amdgcn_mfma_f32_16x16x32_bf16(Ah1, Bl[nt*2+1], a, 0, 0, 0);
            a = __builtin_amdgcn_mfma_f32_16x16x32_bf16(Al0, Bh[nt*2+0], a, 0, 0, 0);
            a = __builtin_amdgcn_mfma_f32_16x16x32_bf16(Al1, Bh[nt*2+1], a, 0, 0, 0);
            acc[nt] = a;
        }
#pragma unroll
        for (int r4 = 0; r4 < 4; ++r4) {
            const int node = nb + quad * 4 + r4;
#pragma unroll
            for (int nt = 0; nt < 4; ++nt)
                PA[node * H + nt * 16 + m16] = acc[nt][r4] + b1v[nt];
#pragma unroll
            for (int nt = 4; nt < 8; ++nt)
                PB[node * H + (nt - 4) * 16 + m16] = acc[nt][r4];
        }
    }
}

// ---------------- edge MLP: CSR + prefetch + LDS run-reduced agg ---------
__global__ __launch_bounds__(256, 2) void k_edge6(
        const float* __restrict__ PA, const float* __restrict__ PB,
        const int* __restrict__ nstart, const int* __restrict__ csrP,
        const float* __restrict__ csrR, const float* __restrict__ csrM,
        const float* __restrict__ W1,   // only row 128 (w1c) used
        const float* __restrict__ W2, const float* __restrict__ b2,
        float* __restrict__ agg) {
    const int tid = threadIdx.x;
    const int lane = tid & 63, wave = tid >> 6;
    const int quad = lane >> 4, m16 = lane & 15;
    const int n0 = blockIdx.x * NPBLK;

    __shared__ float aggld[NPBLK * 68];
    for (int i = tid; i < NPBLK * 68; i += 256) aggld[i] = 0.0f;

    short8 Bh[8], Bl[8];
#pragma unroll
    for (int nt = 0; nt < 4; ++nt) {
#pragma unroll
        for (int kf = 0; kf < 2; ++kf) {
            short8 bh, bl;
#pragma unroll
            for (int j = 0; j < 8; ++j) {
                float w = W2[(kf * 32 + quad * 8 + j) * H + nt * 16 + m16];
                unsigned short hi, lo; splitbf(w, hi, lo);
                bh[j] = (short)hi; bl[j] = (short)lo;
            }
            Bh[nt * 2 + kf] = bh; Bl[nt * 2 + kf] = bl;
        }
    }
    float w1cr[16];
#pragma unroll
    for (int i = 0; i < 16; ++i) {
        int k = (i < 8) ? (quad * 8 + i) : (32 + quad * 8 + (i - 8));
        w1cr[i] = W1[128 * H + k];
    }
    float b2v[4];
#pragma unroll
    for (int nt = 0; nt < 4; ++nt) b2v[nt] = b2[nt * 16 + m16];

    const int start = nstart[n0];
    const int end   = nstart[n0 + NPBLK];
    __syncthreads();

    const int ntiles = (end - start + 15) >> 4;

    float radA = 0.0f, avA[16], bvA[16];
    int rlA = 0;
    int rlqA[4]; float mkqA[4];

    int t = wave;
    bool haveA = t < ntiles;
    if (haveA) {
        const int idx = start + t * 16 + m16;
        const int ss = min(idx, N_EDGES - 1);
        const int pk = csrP[ss];
        radA = csrR[ss];
        const int c = pk & 0xFFFF;
        rlA = pk >> 16;
        const int sb = start + t * 16 + quad * 4;
#pragma unroll
        for (int r4 = 0; r4 < 4; ++r4) {
            int s = sb + r4, s2 = min(s, N_EDGES - 1);
            rlqA[r4] = csrP[s2] >> 16;
            mkqA[r4] = (s < end) ? csrM[s2] : 0.0f;
        }
        const float* par = PA + (n0 + rlA) * H + quad * 8;
        const float* pbr = PB + c * H + quad * 8;
        *(float4*)&avA[0]  = *(const float4*)(par + 0);
        *(float4*)&avA[4]  = *(const float4*)(par + 4);
        *(float4*)&avA[8]  = *(const float4*)(par + 32);
        *(float4*)&avA[12] = *(const float4*)(par + 36);
        *(float4*)&bvA[0]  = *(const float4*)(pbr + 0);
        *(float4*)&bvA[4]  = *(const float4*)(pbr + 4);
        *(float4*)&bvA[8]  = *(const float4*)(pbr + 32);
        *(float4*)&bvA[12] = *(const float4*)(pbr + 36);
    }

    while (haveA) {
        const int tn = t + 4;
        const bool haveB = tn < ntiles;
        float radB = 0.0f, bvB[16];
        int rlB = 0;
        int rlqB[4]; float mkqB[4];
        if (haveB) {
            const int idx = start + tn * 16 + m16;
            const int ss = min(idx, N_EDGES - 1);
            const int pk = csrP[ss];
            radB = csrR[ss];
            const int c = pk & 0xFFFF;
            rlB = pk >> 16;
            const int sb = start + tn * 16 + quad * 4;
#pragma unroll
            for (int r4 = 0; r4 < 4; ++r4) {
                int s = sb + r4, s2 = min(s, N_EDGES - 1);
                rlqB[r4] = csrP[s2] >> 16;
                mkqB[r4] = (s < end) ? csrM[s2] : 0.0f;
            }
            const float* pbr = PB + c * H + quad * 8;
            *(float4*)&bvB[0]  = *(const float4*)(pbr + 0);
            *(float4*)&bvB[4]  = *(const float4*)(pbr + 4);
            *(float4*)&bvB[8]  = *(const float4*)(pbr + 32);
            *(float4*)&bvB[12] = *(const float4*)(pbr + 36);
        }

        short8 Ah0, Ah1, Al0, Al1;
#pragma unroll
        for (int i = 0; i < 8; ++i) {
            unsigned short hi, lo;
            splitbf_t(silu_f(avA[i] + bvA[i] + radA * w1cr[i]), hi, lo);
            Ah0[i] = (short)hi; Al0[i] = (short)lo;
            splitbf_t(silu_f(avA[8+i] + bvA[8+i] + radA * w1cr[8+i]), hi, lo);
            Ah1[i] = (short)hi; Al1[i] = (short)lo;
        }
        f32x4 acc[4];
#pragma unroll
        for (int nt = 0; nt < 4; ++nt) {
            f32x4 a = {0.0f, 0.0f, 0.0f, 0.0f};
            a = __builtin_amdgcn_mfma_f32_16x16x32_bf16(Ah0, Bh[nt*2+0], a, 0, 0, 0);
            a = __builtin_amdgcn_mfma_f32_16x16x32_bf16(Ah1, Bh[nt*2+1], a, 0, 0, 0);
            a = __builtin_amdgcn_mfma_f32_16x16x32_bf16(Ah0, Bl[nt*2+0], a, 0, 0, 0);
            a = __builtin_amdgcn_mfma_f32_16x16x32_bf16(Ah1, Bl[nt*2+1], a, 0, 0, 0);
            a = __builtin_amdgcn_mfma_f32_16x16x32_bf16(Al0, Bh[nt*2+0], a, 0, 0, 0);
            a = __builtin_amdgcn_mfma_f32_16x16x32_bf16(Al1, Bh[nt*2+1], a, 0, 0, 0);
            acc[nt] = a;
        }

#pragma unroll
        for (int nt = 0; nt < 4; ++nt) {
            float oo[4];
#pragma unroll
            for (int r4 = 0; r4 < 4; ++r4)
                oo[r4] = silu_f(acc[nt][r4] + b2v[nt]) * mkqA[r4];
            int cur = rlqA[0]; float s = oo[0];
#pragma unroll
            for (int r4 = 1; r4 < 4; ++r4) {
                if (rlqA[r4] == cur) { s += oo[r4]; }
                else {
                    atomicAdd(&aggld[cur * 68 + nt * 16 + m16], s);
                    cur = rlqA[r4]; s = oo[r4];
                }
            }
            atomicAdd(&aggld[cur * 68 + nt * 16 + m16], s);
        }

        if (haveB) {
            radA = radB; rlA = rlB;
#pragma unroll
            for (int r4 = 0; r4 < 4; ++r4) { rlqA[r4] = rlqB[r4]; mkqA[r4] = mkqB[r4]; }
            const float* par = PA + (n0 + rlA) * H + quad * 8;
            *(float4*)&avA[0]  = *(const float4*)(par + 0);
            *(float4*)&avA[4]  = *(const float4*)(par + 4);
            *(float4*)&avA[8]  = *(const float4*)(par + 32);
            *(float4*)&avA[12] = *(const float4*)(par + 36);
#pragma unroll
            for (int i = 0; i < 16; ++i) bvA[i] = bvB[i];
        }
        t = tn; haveA = haveB;
    }

    __syncthreads();
#pragma unroll
    for (int i = tid; i < NPBLK * 16; i += 256) {
        int n = i >> 4, cb = (i & 15) << 2;
        *(float4*)&agg[(n0 + n) * H + cb] = *(const float4*)&aggld[n * 68 + cb];
    }
}

// ---------------- node MLP via MFMA (2 tiles/wave, no spill) -------------
__global__ __launch_bounds__(64, 1) void k_node_m(
        float* __restrict__ h, const float* __restrict__ agg,
        const float* __restrict__ h0,
        const float* __restrict__ W1, const float* __restrict__ b1,
        const float* __restrict__ W2, const float* __restrict__ b2) {
    const int lane = threadIdx.x;
    const int quad = lane >> 4, m16 = lane & 15;

    short8 B1h[20], B1l[20];   // [nt*5+kf], rows 0..159 (pad >=139 with 0)
#pragma unroll
    for (int nt = 0; nt < 4; ++nt) {
#pragma unroll
        for (int kf = 0; kf < 5; ++kf) {
            short8 bh, bl;
#pragma unroll
            for (int j = 0; j < 8; ++j) {
                int row = kf * 32 + quad * 8 + j;
                float w = (row < NIN) ? W1[row * H + nt * 16 + m16] : 0.0f;
                unsigned short hi, lo; splitbf(w, hi, lo);
                bh[j] = (short)hi; bl[j] = (short)lo;
            }
            B1h[nt * 5 + kf] = bh; B1l[nt * 5 + kf] = bl;
        }
    }
    short8 B2h[8], B2l[8];
#pragma unroll
    for (int nt = 0; nt < 4; ++nt) {
#pragma unroll
        for (int kf = 0; kf < 2; ++kf) {
            short8 bh, bl;
#pragma unroll
            for (int j = 0; j < 8; ++j) {
                float w = W2[(kf * 32 + quad * 8 + j) * H + nt * 16 + m16];
                unsigned short hi, lo; splitbf(w, hi, lo);
                bh[j] = (short)hi; bl[j] = (short)lo;
            }
            B2h[nt * 2 + kf] = bh; B2l[nt * 2 + kf] = bl;
        }
    }
    float b1v[4], b2v[4];
#pragma unroll
    for (int nt = 0; nt < 4; ++nt) {
        b1v[nt] = b1[nt * 16 + m16];
        b2v[nt] = b2[nt * 16 + m16];
    }

    __shared__ float tld[16 * 68];   // stride 68: no 4-way bank conflict

    for (int t = 0; t < 2; ++t) {
        const int nb = (blockIdx.x * 2 + t) * 16;
        float a1[5][8];
        const float* hp = h + (nb + m16) * H + quad * 8;
        const float* ap = agg + (nb + m16) * H + quad * 8;
        *(float4*)&a1[0][0] = *(const float4*)(hp + 0);
        *(float4*)&a1[0][4] = *(const float4*)(hp + 4);
        *(float4*)&a1[1][0] = *(const float4*)(hp + 32);
        *(float4*)&a1[1][4] = *(const float4*)(hp + 36);
        *(float4*)&a1[2][0] = *(const float4*)(ap + 0);
        *(float4*)&a1[2][4] = *(const float4*)(ap + 4);
        *(float4*)&a1[3][0] = *(const float4*)(ap + 32);
        *(float4*)&a1[3][4] = *(const float4*)(ap + 36);
        const float* h0p = h0 + (nb + m16) * F_IN;
#pragma unroll
        for (int j = 0; j < 8; ++j) {
            int kk = quad * 8 + j;
            a1[4][j] = (kk < F_IN) ? h0p[kk] : 0.0f;
        }
        short8 A1h[5], A1l[5];
#pragma unroll
        for (int kf = 0; kf < 5; ++kf) {
            short8 ah, al;
#pragma unroll
            for (int j = 0; j < 8; ++j) {
                unsigned short hi, lo; splitbf_t(a1[kf][j], hi, lo);
                ah[j] = (short)hi; al[j] = (short)lo;
            }
            A1h[kf] = ah; A1l[kf] = al;
        }
        f32x4 acc[4];
#pragma unroll
        for (int nt = 0; nt < 4; ++nt) {
            f32x4 a = {0.0f, 0.0f, 0.0f, 0.0f};
#pragma unroll
            for (int kf = 0; kf < 5; ++kf)
                a = __builtin_amdgcn_mfma_f32_16x16x32_bf16(A1h[kf], B1h[nt*5+kf], a, 0, 0, 0);
#pragma unroll
            for (int kf = 0; kf < 5; ++kf)
                a = __builtin_amdgcn_mfma_f32_16x16x32_bf16(A1h[kf], B1l[nt*5+kf], a, 0, 0, 0);
#pragma unroll
            for (int kf = 0; kf < 5; ++kf)
                a = __builtin_amdgcn_mfma_f32_16x16x32_bf16(A1l[kf], B1h[nt*5+kf], a, 0, 0, 0);
            acc[nt] = a;
        }
#pragma unroll
        for (int r4 = 0; r4 < 4; ++r4)
#pragma unroll
            for (int nt = 0; nt < 4; ++nt)
                tld[(quad * 4 + r4) * 68 + nt * 16 + m16] =
                    silu_f(acc[nt][r4] + b1v[nt]);
        __syncthreads();
        float a2[16];
        *(float4*)&a2[0]  = *(const float4*)&tld[m16 * 68 + quad * 8 + 0];
        *(float4*)&a2[4]  = *(const float4*)&tld[m16 * 68 + quad * 8 + 4];
        *(float4*)&a2[8]  = *(const float4*)&tld[m16 * 68 + quad * 8 + 32];
        *(float4*)&a2[12] = *(const float4*)&tld[m16 * 68 + quad * 8 + 36];
        short8 A2h0, A2h1, A2l0, A2l1;
#pragma unroll
        for (int j = 0; j < 8; ++j) {
            unsigned short hi, lo;
            splitbf_t(a2[j], hi, lo);     A2h0[j] = (short)hi; A2l0[j] = (short)lo;
            splitbf_t(a2[8+j], hi, lo);   A2h1[j] = (short)hi; A2l1[j] = (short)lo;
        }
        f32x4 acc2[4];
#pragma unroll
        for (int nt = 0; nt < 4; ++nt) {
            f32x4 a = {0.0f, 0.0f, 0.0f, 0.0f};
            a = __builtin_amdgcn_mfma_f32_16x16x32_bf16(A2h0, B2h[nt*2+0], a, 0, 0, 0);
            a = __builtin_amdgcn_mfma_f32_16x16x32_bf16(A2h1, B2h[nt*2+1], a, 0, 0, 0);
            a = __builtin_amdgcn_mfma_f32_16x16x32_bf16(A2h0, B2l[nt*2+0], a, 0, 0, 0);
            a = __builtin_amdgcn_mfma_f32_16x16x32_bf16(A2h1, B2l[nt*2+1], a, 0, 0, 0);
            a = __builtin_amdgcn_mfma_f32_16x16x32_bf16(A2l0, B2h[nt*2+0], a, 0, 0, 0);
            a = __builtin_amdgcn_mfma_f32_16x16x32_bf16(A2l1, B2h[nt*2+1], a, 0, 0, 0);
            acc2[nt] = a;
        }
#pragma unroll
        for (int r4 = 0; r4 < 4; ++r4) {
            const int node = nb + quad * 4 + r4;
#pragma unroll
            for (int nt = 0; nt < 4; ++nt)
                h[node * H + nt * 16 + m16] = acc2[nt][r4] + b2v[nt];
        }
        __syncthreads();
    }
}

// ---------------- node decoder via MFMA (2 tiles/wave, no spill) ---------
__global__ __launch_bounds__(64, 1) void k_dec_m(
        float* __restrict__ h, const float* __restrict__ nmask,
        const float* __restrict__ W1, const float* __restrict__ b1,
        const float* __restrict__ W2, const float* __restrict__ b2) {
    const int lane = threadIdx.x;
    const int quad = lane >> 4, m16 = lane & 15;

    short8 B1h[8], B1l[8], B2h[8], B2l[8];
#pragma unroll
    for (int nt = 0; nt < 4; ++nt) {
#pragma unroll
        for (int kf = 0; kf < 2; ++kf) {
            short8 bh1, bl1, bh2, bl2;
#pragma unroll
            for (int j = 0; j < 8; ++j) {
                int row = kf * 32 + quad * 8 + j;
                unsigned short hi, lo;
                splitbf(W1[row * H + nt * 16 + m16], hi, lo);
                bh1[j] = (short)hi; bl1[j] = (short)lo;
                splitbf(W2[row * H + nt * 16 + m16], hi, lo);
                bh2[j] = (short)hi; bl2[j] = (short)lo;
            }
            B1h[nt*2+kf] = bh1; B1l[nt*2+kf] = bl1;
            B2h[nt*2+kf] = bh2; B2l[nt*2+kf] = bl2;
        }
    }
    float b1v[4], b2v[4];
#pragma unroll
    for (int nt = 0; nt < 4; ++nt) {
        b1v[nt] = b1[nt * 16 + m16];
        b2v[nt] = b2[nt * 16 + m16];
    }
    __shared__ float tld[16 * 68];

    for (int t = 0; t < 2; ++t) {
        const int nb = (blockIdx.x * 2 + t) * 16;
        const float* hp = h + (nb + m16) * H + quad * 8;
        float av[16];
        *(float4*)&av[0]  = *(const float4*)(hp + 0);
        *(float4*)&av[4]  = *(const float4*)(hp + 4);
        *(float4*)&av[8]  = *(const float4*)(hp + 32);
        *(float4*)&av[12] = *(const float4*)(hp + 36);
        short8 Ah0, Ah1, Al0, Al1;
#pragma unroll
        for (int j = 0; j < 8; ++j) {
            unsigned short hi, lo;
            splitbf_t(av[j], hi, lo);     Ah0[j] = (short)hi; Al0[j] = (short)lo;
            splitbf_t(av[8+j], hi, lo);   Ah1[j] = (short)hi; Al1[j] = (short)lo;
        }
        f32x4 acc[4];
#pragma unroll
        for (int nt = 0; nt < 4; ++nt) {
            f32x4 a = {0.0f, 0.0f, 0.0f, 0.0f};
            a = __builtin_amdgcn_mfma_f32_16x16x32_bf16(Ah0, B1h[nt*2+0], a, 0, 0, 0);
            a = __builtin_amdgcn_mfma_f32_16x16x32_bf16(Ah1, B1h[nt*2+1], a, 0, 0, 0);
            a = __builtin_amdgcn_mfma_f32_16x16x32_bf16(Ah0, B1l[nt*2+0], a, 0, 0, 0);
            a = __builtin_amdgcn_mfma_f32_16x16x32_bf16(Ah1, B1l[nt*2+1], a, 0, 0, 0);
            a = __builtin_amdgcn_mfma_f32_16x16x32_bf16(Al0, B1h[nt*2+0], a, 0, 0, 0);
            a = __builtin_amdgcn_mfma_f32_16x16x32_bf16(Al1, B1h[nt*2+1], a, 0, 0, 0);
            acc[nt] = a;
        }
#pragma unroll
        for (int r4 = 0; r4 < 4; ++r4)
#pragma unroll
            for (int nt = 0; nt < 4; ++nt)
                tld[(quad * 4 + r4) * 68 + nt * 16 + m16] =
                    silu_f(acc[nt][r4] + b1v[nt]);
        __syncthreads();
        float a2[16];
        *(float4*)&a2[0]  = *(const float4*)&tld[m16 * 68 + quad * 8 + 0];
        *(float4*)&a2[4]  = *(const float4*)&tld[m16 * 68 + quad * 8 + 4];
        *(float4*)&a2[8]  = *(const float4*)&tld[m16 * 68 + quad * 8 + 32];
        *(float4*)&a2[12] = *(const float4*)&tld[m16 * 68 + quad * 8 + 36];
        short8 A2h0, A2h1, A2l0, A2l1;
#pragma unroll
        for (int j = 0; j < 8; ++j) {
            unsigned short hi, lo;
            splitbf_t(a2[j], hi, lo);     A2h0[j] = (short)hi; A2l0[j] = (short)lo;
            splitbf_t(a2[8+j], hi, lo);   A2h1[j] = (short)hi; A2l1[j] = (short)lo;
        }
        f32x4 acc2[4];
#pragma unroll
        for (int nt = 0; nt < 4; ++nt) {
            f32x4 a = {0.0f, 0.0f, 0.0f, 0.0f};
            a = __builtin_amdgcn_mfma_f32_16x16x32_bf16(A2h0, B2h[nt*2+0], a, 0, 0, 0);
            a = __builtin_amdgcn_mfma_f32_16x16x32_bf16(A2h1, B2h[nt*2+1], a, 0, 0, 0);
            a = __builtin_amdgcn_mfma_f32_16x16x32_bf16(A2h0, B2l[nt*2+0], a, 0, 0, 0);
            a = __builtin_amdgcn_mfma_f32_16x16x32_bf16(A2h1, B2l[nt*2+1], a, 0, 0, 0);
            a = __builtin_amdgcn_mfma_f32_16x16x32_bf16(A2l0, B2h[nt*2+0], a, 0, 0, 0);
            a = __builtin_amdgcn_mfma_f32_16x16x32_bf16(A2l1, B2h[nt*2+1], a, 0, 0, 0);
            acc2[nt] = a;
        }
#pragma unroll
        for (int r4 = 0; r4 < 4; ++r4) {
            const int node = nb + quad * 4 + r4;
            const float nm = nmask[node];
#pragma unroll
            for (int nt = 0; nt < 4; ++nt)
                h[node * H + nt * 16 + m16] = (acc2[nt][r4] + b2v[nt]) * nm;
        }
        __syncthreads();
    }
}

// ---------------- pool + graph decoder + reaction aggregation ------------
__global__ __launch_bounds__(64) void k_graph(
        const float* __restrict__ h, const int* __restrict__ rid,
        const float* __restrict__ rsign,
        const float* __restrict__ W1, const float* __restrict__ b1,
        const float* __restrict__ W2, const float* __restrict__ b2,
        float* __restrict__ pred) {
    const int g = blockIdx.x;
    const int lane = threadIdx.x;
    float hgv = 0.0f;
#pragma unroll
    for (int m = 0; m < NN_PER_G; ++m)
        hgv += h[(g * NN_PER_G + m) * H + lane];
    __shared__ __align__(16) float hgs[64];
    hgs[lane] = hgv;
    __syncthreads();
    float acc = b1[lane];
#pragma unroll
    for (int k = 0; k < H; ++k)
        acc += hgs[k] * W1[k * H + lane];
    float part = silu_f(acc) * W2[lane];
#pragma unroll
    for (int off = 32; off > 0; off >>= 1)
        part += __shfl_down(part, off);
    if (lane == 0)
        atomAddF(&pred[rid[g]], (part + b2[0]) * rsign[g]);
}

extern "C" void kernel_launch(void* const* d_in, const int* in_sizes, int n_in,
                              void* d_out, int out_size, void* d_ws, size_t ws_size,
                              hipStream_t stream) {
    const float* h0      = (const float*)d_in[0];
    const float* pos     = (const float*)d_in[1];
    const int*   edges   = (const int*)d_in[2];
    const float* nmask   = (const float*)d_in[3];
    const float* emask   = (const float*)d_in[4];
    const int*   rid     = (const int*)d_in[5];
    const float* rsign   = (const float*)d_in[6];
    const float* emb_w   = (const float*)d_in[7];
    const float* emb_b   = (const float*)d_in[8];
    const float* edge_w1 = (const float*)d_in[9];
    const float* edge_b1 = (const float*)d_in[10];
    const float* edge_w2 = (const float*)d_in[11];
    const float* edge_b2 = (const float*)d_in[12];
    const float* node_w1 = (const float*)d_in[13];
    const float* node_b1 = (const float*)d_in[14];
    const float* node_w2 = (const float*)d_in[15];
    const float* node_b2 = (const float*)d_in[16];
    const float* dec_w1  = (const float*)d_in[17];
    const float* dec_b1  = (const float*)d_in[18];
    const float* dec_w2  = (const float*)d_in[19];
    const float* dec_b2  = (const float*)d_in[20];
    const float* g_w1    = (const float*)d_in[21];
    const float* g_b1    = (const float*)d_in[22];
    const float* g_w2    = (const float*)d_in[23];
    const float* g_b2    = (const float*)d_in[24];

    float* h      = (float*)d_ws;            // N*H
    float* agg    = h + N_NODES * H;         // N*H
    float* radial = agg + N_NODES * H;       // E
    float* PA     = radial + N_EDGES;        // N*H
    float* PB     = PA + N_NODES * H;        // N*H
    float* csrR   = PB + N_NODES * H;        // E
    float* csrM   = csrR + N_EDGES;          // E
    int*   csrP   = (int*)(csrM + N_EDGES);  // E
    int*   deg    = csrP + N_EDGES;          // N
    int*   off    = deg + N_NODES;           // N
    int*   bsum   = off + N_NODES;           // 256
    int*   bbase  = bsum + 256;              // 256
    int*   nstart = bbase + 256;             // N+1
    int*   cursor = nstart + N_NODES + 1;    // N
    float* pred   = (float*)d_out;

    hipMemsetAsync(d_out, 0, R_REACT * sizeof(float), stream);
    hipMemsetAsync(deg, 0, N_NODES * sizeof(int), stream);

    k_embed<<<(N_NODES * H) / 256, 256, 0, stream>>>(h0, emb_w, emb_b, h);
    k_radial<<<N_EDGES / 256, 256, 0, stream>>>(edges, pos, radial);
    k_hist<<<N_EDGES / 256, 256, 0, stream>>>(edges, deg);
    k_scan_blk<<<256, 128, 0, stream>>>(deg, off, bsum);
    k_scan_top<<<1, 256, 0, stream>>>(bsum, bbase);
    k_cursor<<<N_NODES / 256, 256, 0, stream>>>(off, bbase, nstart, cursor);
    k_fill<<<N_EDGES / 256, 256, 0, stream>>>(edges, radial, emask, cursor,
                                              csrP, csrR, csrM);

    for (int i = 0; i < L_LAYERS; ++i) {
        k_nodeproj_m<<<N_NODES / 32, 64, 0, stream>>>(
            h, edge_w1 + i * EIN * H, edge_b1 + i * H, PA, PB);
        k_edge6<<<N_NODES / NPBLK, 256, 0, stream>>>(
            PA, PB, nstart, csrP, csrR, csrM,
            edge_w1 + i * EIN * H,
            edge_w2 + i * H * H, edge_b2 + i * H, agg);
        k_node_m<<<N_NODES / 32, 64, 0, stream>>>(
            h, agg, h0,
            node_w1 + i * NIN * H, node_b1 + i * H,
            node_w2 + i * H * H,   node_b2 + i * H);
    }
    k_dec_m<<<N_NODES / 32, 64, 0, stream>>>(h, nmask, dec_w1, dec_b1,
                                             dec_w2, dec_b2);
    k_graph<<<G_GRAPHS, 64, 0, stream>>>(h, rid, rsign, g_w1, g_b1, g_w2,
                                         g_b2, pred);
}